// Round 4
// baseline (267.568 us; speedup 1.0000x reference)
//
#include <hip/hip_runtime.h>
#include <hip/hip_fp16.h>

#define EPS 1e-4f
constexpr int N_DIM = 1024;
constexpr int M_DIM = 1024;
constexpr int BATCH = 64;
constexpr int CH    = 4;              // n-chunks for col sweeps
constexpr int ROWS  = N_DIM / CH;     // 256

// Factor form: out = r[n]*(s+EPS)*c[m]; sweeps alternate
//   col: traw[m] = sum_{n<R} r[n]*(s+EPS),  r = 1/uraw
//   row: uraw[n] = sum_{m<C} c[m]*(s+EPS),  c = 1/traw
// fp16 path: iter0 converts h = fp16(s+EPS) (0 beyond C); iters 1..9 sweep h.

// ===========================================================================
// fp16 fast path
// ===========================================================================

// iter 0 (col, r==1) fused with conversion. grid (4*CH, B), 256 thr.
__global__ __launch_bounds__(256)
void col_first_conv(const float* __restrict__ s,
                    const int* __restrict__ nrows,
                    const int* __restrict__ ncols,
                    __half* __restrict__ h,
                    float* __restrict__ tpart) {
    const int b  = blockIdx.y;
    const int mt = blockIdx.x & 3;
    const int ch = blockIdx.x >> 2;
    const int R = nrows[b], C = ncols[b];
    const int lane = threadIdx.x & 63, wv = threadIdx.x >> 6;
    const int m = mt * 256 + lane * 4;
    const int n0 = ch * ROWS;
    const int nend = min(R, n0 + ROWS);
    const size_t base = (size_t)b * N_DIM * M_DIM;

    float4 acc = make_float4(0.f, 0.f, 0.f, 0.f);
    if (mt * 256 < C) {
        for (int n = n0 + wv; n < nend; n += 4) {
            float4 v = *(const float4*)(s + base + (size_t)n * M_DIM + m);
            v.x = (m + 0 < C) ? v.x + EPS : 0.f;
            v.y = (m + 1 < C) ? v.y + EPS : 0.f;
            v.z = (m + 2 < C) ? v.z + EPS : 0.f;
            v.w = (m + 3 < C) ? v.w + EPS : 0.f;
            acc.x += v.x; acc.y += v.y; acc.z += v.z; acc.w += v.w;
            union { __half2 h2[2]; uint2 u2; } pk;
            pk.h2[0] = __floats2half2_rn(v.x, v.y);
            pk.h2[1] = __floats2half2_rn(v.z, v.w);
            *(uint2*)(h + base + (size_t)n * M_DIM + m) = pk.u2;
        }
    } else {
        const uint2 z = make_uint2(0u, 0u);
        for (int n = n0 + wv; n < nend; n += 4)
            *(uint2*)(h + base + (size_t)n * M_DIM + m) = z;
    }
    __shared__ float4 red[4][64];
    red[wv][lane] = acc;
    __syncthreads();
    if (wv == 0) {
        float4 a0 = red[0][lane], a1 = red[1][lane],
               a2 = red[2][lane], a3 = red[3][lane];
        float4 t = make_float4(a0.x + a1.x + a2.x + a3.x,
                               a0.y + a1.y + a2.y + a3.y,
                               a0.z + a1.z + a2.z + a3.z,
                               a0.w + a1.w + a2.w + a3.w);
        *(float4*)(tpart + (size_t)(ch * BATCH + b) * M_DIM + m) = t;
    }
}

// col sweep on h (iters 2,4,6,8). grid (2*CH, B): 2 mtiles of 512 cols.
__global__ __launch_bounds__(256)
void col_h(const __half* __restrict__ h,
           const int* __restrict__ nrows,
           const int* __restrict__ ncols,
           const float* __restrict__ u,
           float* __restrict__ tpart) {
    const int b  = blockIdx.y;
    const int mt = blockIdx.x & 1;
    const int ch = blockIdx.x >> 1;
    const int R = nrows[b], C = ncols[b];
    const int lane = threadIdx.x & 63, wv = threadIdx.x >> 6;
    const int m = mt * 512 + lane * 8;
    const int n0 = ch * ROWS;
    const int nend = min(R, n0 + ROWS);
    const size_t base = (size_t)b * N_DIM * M_DIM;

    __shared__ float rlds[ROWS];
    {   // 256 threads == ROWS
        float uu = u[b * N_DIM + n0 + threadIdx.x];
        rlds[threadIdx.x] = (uu == 0.f) ? 1.f : 1.f / uu;
    }
    __syncthreads();

    float acc[8] = {0.f, 0.f, 0.f, 0.f, 0.f, 0.f, 0.f, 0.f};
    if (mt * 512 < C) {
        for (int n = n0 + wv; n < nend; n += 4) {
            uint4 raw = *(const uint4*)(h + base + (size_t)n * M_DIM + m);
            const float rn = rlds[n - n0];
            const __half2* hp = (const __half2*)&raw;
#pragma unroll
            for (int k = 0; k < 4; ++k) {
                float2 f = __half22float2(hp[k]);
                acc[2 * k]     += rn * f.x;
                acc[2 * k + 1] += rn * f.y;
            }
        }
    }
    __shared__ float red[4][64 * 8];
#pragma unroll
    for (int k = 0; k < 8; ++k) red[wv][lane * 8 + k] = acc[k];
    __syncthreads();
    if (wv == 0) {
        float t[8];
#pragma unroll
        for (int k = 0; k < 8; ++k)
            t[k] = red[0][lane * 8 + k] + red[1][lane * 8 + k] +
                   red[2][lane * 8 + k] + red[3][lane * 8 + k];
        float* tp = tpart + (size_t)(ch * BATCH + b) * M_DIM + m;
        *(float4*)tp       = make_float4(t[0], t[1], t[2], t[3]);
        *(float4*)(tp + 4) = make_float4(t[4], t[5], t[6], t[7]);
    }
}

// row sweep on h (iters 1,3,5,7,9). grid (32, B): 32 rows/block, 8/wave.
template <bool WRITE_C>
__global__ __launch_bounds__(256)
void row_h(const __half* __restrict__ h,
           const int* __restrict__ nrows,
           const int* __restrict__ ncols,
           const float* __restrict__ tpart,
           float* __restrict__ u,
           float* __restrict__ cOut) {
    const int b = blockIdx.y;
    const int R = nrows[b], C = ncols[b];
    const int n0 = blockIdx.x * 32;
    if (n0 >= R) return;
    const size_t base = (size_t)b * N_DIM * M_DIM;

    __shared__ float clds[M_DIM];
    {
        const int t4 = threadIdx.x * 4;
        float4 sum = make_float4(0.f, 0.f, 0.f, 0.f);
#pragma unroll
        for (int ch = 0; ch < CH; ++ch) {
            float4 p = *(const float4*)(tpart + (size_t)(ch * BATCH + b) * M_DIM + t4);
            sum.x += p.x; sum.y += p.y; sum.z += p.z; sum.w += p.w;
        }
        float4 cv;
        cv.x = (sum.x == 0.f) ? 1.f : 1.f / sum.x;
        cv.y = (sum.y == 0.f) ? 1.f : 1.f / sum.y;
        cv.z = (sum.z == 0.f) ? 1.f : 1.f / sum.z;
        cv.w = (sum.w == 0.f) ? 1.f : 1.f / sum.w;
        *(float4*)&clds[t4] = cv;
        if (WRITE_C && blockIdx.x == 0)
            *(float4*)(cOut + b * M_DIM + t4) = cv;
    }
    __syncthreads();

    const int lane = threadIdx.x & 63, wv = threadIdx.x >> 6;
    const bool hi = (C > 512);           // cols 512..1023 are zero otherwise
#pragma unroll 2
    for (int i = 0; i < 8; ++i) {
        const int n = n0 + wv * 8 + i;
        if (n >= R) break;
        const __half* hrow = h + base + (size_t)n * M_DIM;
        float sum = 0.f;
        {
            uint4 raw = *(const uint4*)(hrow + lane * 8);
            const __half2* hp = (const __half2*)&raw;
            const float* cl = &clds[lane * 8];
#pragma unroll
            for (int k = 0; k < 4; ++k) {
                float2 f = __half22float2(hp[k]);
                sum += f.x * cl[2 * k] + f.y * cl[2 * k + 1];
            }
        }
        if (hi) {
            uint4 raw = *(const uint4*)(hrow + 512 + lane * 8);
            const __half2* hp = (const __half2*)&raw;
            const float* cl = &clds[512 + lane * 8];
#pragma unroll
            for (int k = 0; k < 4; ++k) {
                float2 f = __half22float2(hp[k]);
                sum += f.x * cl[2 * k] + f.y * cl[2 * k + 1];
            }
        }
#pragma unroll
        for (int off = 32; off; off >>= 1) sum += __shfl_down(sum, off);
        if (lane == 0) u[b * N_DIM + n] = sum;
    }
}

// finalize on f32 s (fp16 never touches the output numerator).
__global__ __launch_bounds__(256)
void finalize(const float* __restrict__ s,
              const int* __restrict__ nrows,
              const int* __restrict__ ncols,
              const float* __restrict__ u,
              const float* __restrict__ c,
              float* __restrict__ out) {
    const int n = blockIdx.x;
    const int b = blockIdx.y;
    const int R = nrows[b], C = ncols[b];
    const size_t base = ((size_t)b * N_DIM + n) * M_DIM;
    const int m = threadIdx.x * 4;

    float4 o = make_float4(0.f, 0.f, 0.f, 0.f);
    if (n < R && m < C) {
        float uu = u[b * N_DIM + n];
        float rn = (uu == 0.f) ? 1.f : 1.f / uu;
        float4 v  = *(const float4*)(s + base + m);
        float4 cc = *(const float4*)(c + b * M_DIM + m);
        o.x = (m + 0 < C) ? (v.x + EPS) * rn * cc.x : 0.f;
        o.y = (m + 1 < C) ? (v.y + EPS) * rn * cc.y : 0.f;
        o.z = (m + 2 < C) ? (v.z + EPS) * rn * cc.z : 0.f;
        o.w = (m + 3 < C) ? (v.w + EPS) * rn * cc.w : 0.f;
    }
    *(float4*)(out + base + m) = o;
}

// ===========================================================================
// f32 fallback (round-3 kernels) for small ws
// ===========================================================================
template <bool FIRST, int CHUNKS>
__global__ __launch_bounds__(256)
void col_sweep(const float* __restrict__ s, const int* __restrict__ nrows,
               const int* __restrict__ ncols, const float* __restrict__ u,
               float* __restrict__ tpart) {
    const int b  = blockIdx.y;
    const int mt = blockIdx.x & 3;
    const int ch = blockIdx.x >> 2;
    const int R = nrows[b], C = ncols[b];
    const int lane = threadIdx.x & 63, wv = threadIdx.x >> 6;
    const int m0 = mt * 256;
    const int m  = m0 + lane * 4;
    constexpr int RW = N_DIM / CHUNKS;
    const int n0 = ch * RW;
    const int nend = min(R, n0 + RW);

    __shared__ float rlds[RW > 1024 ? 1 : RW];
    if (!FIRST) {
        for (int i = threadIdx.x; i < RW; i += 256) {
            float uu = u[b * N_DIM + n0 + i];
            rlds[i] = (uu == 0.f) ? 1.f : 1.f / uu;
        }
        __syncthreads();
    }
    float4 acc = make_float4(0.f, 0.f, 0.f, 0.f);
    if (m0 < C) {
        const float* __restrict__ sb = s + (size_t)b * N_DIM * M_DIM;
#pragma unroll 4
        for (int n = n0 + wv; n < nend; n += 4) {
            float4 v = *(const float4*)(sb + (size_t)n * M_DIM + m);
            float rn = FIRST ? 1.f : rlds[n - n0];
            acc.x += rn * (v.x + EPS); acc.y += rn * (v.y + EPS);
            acc.z += rn * (v.z + EPS); acc.w += rn * (v.w + EPS);
        }
    }
    __shared__ float4 red[4][64];
    red[wv][lane] = acc;
    __syncthreads();
    if (wv == 0) {
        float4 a0 = red[0][lane], a1 = red[1][lane],
               a2 = red[2][lane], a3 = red[3][lane];
        float4 t = make_float4(a0.x + a1.x + a2.x + a3.x, a0.y + a1.y + a2.y + a3.y,
                               a0.z + a1.z + a2.z + a3.z, a0.w + a1.w + a2.w + a3.w);
        *(float4*)(tpart + ((size_t)(ch * BATCH + b)) * M_DIM + m) = t;
    }
}

template <int CHUNKS, bool WRITE_C>
__global__ __launch_bounds__(256)
void row_sweep(const float* __restrict__ s, const int* __restrict__ nrows,
               const int* __restrict__ ncols, const float* __restrict__ tpart,
               float* __restrict__ u, float* __restrict__ cOut) {
    const int b = blockIdx.y;
    const int R = nrows[b], C = ncols[b];
    const int n0 = blockIdx.x * 16;
    if (n0 >= R) return;
    __shared__ float clds[M_DIM];
    {
        const int t4 = threadIdx.x;
        float4 sum = make_float4(0.f, 0.f, 0.f, 0.f);
#pragma unroll
        for (int ch = 0; ch < CHUNKS; ++ch) {
            float4 p = *(const float4*)(tpart + ((size_t)(ch * BATCH + b)) * M_DIM + t4 * 4);
            sum.x += p.x; sum.y += p.y; sum.z += p.z; sum.w += p.w;
        }
        float4 cv;
        cv.x = (sum.x == 0.f) ? 1.f : 1.f / sum.x;
        cv.y = (sum.y == 0.f) ? 1.f : 1.f / sum.y;
        cv.z = (sum.z == 0.f) ? 1.f : 1.f / sum.z;
        cv.w = (sum.w == 0.f) ? 1.f : 1.f / sum.w;
        *(float4*)&clds[t4 * 4] = cv;
        if (WRITE_C && blockIdx.x == 0)
            *(float4*)(cOut + b * M_DIM + t4 * 4) = cv;
    }
    __syncthreads();
    const int lane = threadIdx.x & 63, wv = threadIdx.x >> 6;
    const int C4 = C >> 2;
#pragma unroll
    for (int i = 0; i < 4; ++i) {
        const int n = n0 + wv * 4 + i;
        if (n >= R) break;
        const float* __restrict__ srow = s + ((size_t)b * N_DIM + n) * M_DIM;
        float sum = 0.f;
        for (int j = lane; j < C4; j += 64) {
            float4 v  = ((const float4*)srow)[j];
            float4 cc = *(const float4*)&clds[j * 4];
            sum += (v.x + EPS) * cc.x + (v.y + EPS) * cc.y +
                   (v.z + EPS) * cc.z + (v.w + EPS) * cc.w;
        }
        for (int mm = (C4 << 2) + lane; mm < C; mm += 64)
            sum += (srow[mm] + EPS) * clds[mm];
#pragma unroll
        for (int off = 32; off; off >>= 1) sum += __shfl_down(sum, off);
        if (lane == 0) u[b * N_DIM + n] = sum;
    }
}

// ===========================================================================
extern "C" void kernel_launch(void* const* d_in, const int* in_sizes, int n_in,
                              void* d_out, int out_size, void* d_ws, size_t ws_size,
                              hipStream_t stream) {
    const float* s     = (const float*)d_in[0];
    const int*   nrows = (const int*)d_in[1];
    const int*   ncols = (const int*)d_in[2];
    float*       out   = (float*)d_out;

    const size_t hElems   = (size_t)BATCH * N_DIM * M_DIM;
    const size_t need_f16 = hElems * 2 +
                            ((size_t)CH * BATCH * M_DIM + BATCH * N_DIM + BATCH * M_DIM) * 4;

    if (ws_size >= need_f16) {
        __half* h     = (__half*)d_ws;
        float*  tpart = (float*)(h + hElems);
        float*  u     = tpart + (size_t)CH * BATCH * M_DIM;
        float*  c     = u + (size_t)BATCH * N_DIM;

        dim3 colGrid1(4 * CH, BATCH);   // conversion sweep
        dim3 colGridH(2 * CH, BATCH);
        dim3 rowGridH(32, BATCH);

        col_first_conv<<<colGrid1, 256, 0, stream>>>(s, nrows, ncols, h, tpart);   // i=0
        row_h<false><<<rowGridH, 256, 0, stream>>>(h, nrows, ncols, tpart, u, c);  // i=1
        for (int k = 0; k < 3; ++k) {                                              // i=2..7
            col_h<<<colGridH, 256, 0, stream>>>(h, nrows, ncols, u, tpart);
            row_h<false><<<rowGridH, 256, 0, stream>>>(h, nrows, ncols, tpart, u, c);
        }
        col_h<<<colGridH, 256, 0, stream>>>(h, nrows, ncols, u, tpart);            // i=8
        row_h<true><<<rowGridH, 256, 0, stream>>>(h, nrows, ncols, tpart, u, c);   // i=9
        finalize<<<dim3(N_DIM, BATCH), 256, 0, stream>>>(s, nrows, ncols, u, c, out);
        return;
    }

    // f32 fallback
    const size_t need4 = (size_t)(4 * BATCH * M_DIM + BATCH * N_DIM + BATCH * M_DIM) * 4;
    if (ws_size >= need4) {
        float* tpart = (float*)d_ws;
        float* u = tpart + (size_t)4 * BATCH * M_DIM;
        float* c = u + (size_t)BATCH * N_DIM;
        dim3 colGrid(16, BATCH), rowGrid(64, BATCH);
        col_sweep<true, 4><<<colGrid, 256, 0, stream>>>(s, nrows, ncols, u, tpart);
        row_sweep<4, false><<<rowGrid, 256, 0, stream>>>(s, nrows, ncols, tpart, u, c);
        for (int k = 1; k < 4; ++k) {
            col_sweep<false, 4><<<colGrid, 256, 0, stream>>>(s, nrows, ncols, u, tpart);
            row_sweep<4, false><<<rowGrid, 256, 0, stream>>>(s, nrows, ncols, tpart, u, c);
        }
        col_sweep<false, 4><<<colGrid, 256, 0, stream>>>(s, nrows, ncols, u, tpart);
        row_sweep<4, true><<<rowGrid, 256, 0, stream>>>(s, nrows, ncols, tpart, u, c);
        finalize<<<dim3(N_DIM, BATCH), 256, 0, stream>>>(s, nrows, ncols, u, c, out);
    } else {
        float* tpart = (float*)d_ws;
        float* u = tpart + (size_t)BATCH * M_DIM;
        float* c = u + (size_t)BATCH * N_DIM;
        dim3 colGrid(4, BATCH), rowGrid(64, BATCH);
        col_sweep<true, 1><<<colGrid, 256, 0, stream>>>(s, nrows, ncols, u, tpart);
        row_sweep<1, false><<<rowGrid, 256, 0, stream>>>(s, nrows, ncols, tpart, u, c);
        for (int k = 1; k < 4; ++k) {
            col_sweep<false, 1><<<colGrid, 256, 0, stream>>>(s, nrows, ncols, u, tpart);
            row_sweep<1, false><<<rowGrid, 256, 0, stream>>>(s, nrows, ncols, tpart, u, c);
        }
        col_sweep<false, 1><<<colGrid, 256, 0, stream>>>(s, nrows, ncols, u, tpart);
        row_sweep<1, true><<<rowGrid, 256, 0, stream>>>(s, nrows, ncols, tpart, u, c);
        finalize<<<dim3(N_DIM, BATCH), 256, 0, stream>>>(s, nrows, ncols, u, c, out);
    }
}

// Round 5
// 239.038 us; speedup vs baseline: 1.1194x; 1.1194x over previous
//
#include <hip/hip_runtime.h>
#include <hip/hip_fp16.h>

#define EPS 1e-4f
constexpr int N_DIM = 1024;
constexpr int M_DIM = 1024;
constexpr int BATCH = 64;
constexpr int CH    = 16;             // n-chunks for all col sweeps
constexpr int CROWS = N_DIM / CH;     // 64 rows per chunk

// Factor form: out = r[n]*(s+EPS)*c[m]; sweeps alternate
//   col: traw[m] = sum_{n<R} r[n]*(s+EPS),  r = 1/uraw
//   row: uraw[n] = sum_{m<C} c[m]*(s+EPS),  c = 1/traw
// fp16 path: iter0 converts h = fp16(s+EPS) (0 beyond C); iters 1..9 sweep h.
// Tail discipline: every sweep block touches <= 64KB so no block exceeds ~3us.

// ===========================================================================
// fp16 fast path
// ===========================================================================

// iter 0 (col, r==1) fused with conversion. grid (4 mt * CH, B), 256 thr.
__global__ __launch_bounds__(256)
void col_first_conv(const float* __restrict__ s,
                    const int* __restrict__ nrows,
                    const int* __restrict__ ncols,
                    __half* __restrict__ h,
                    float* __restrict__ tpart) {
    const int b  = blockIdx.y;
    const int mt = blockIdx.x & 3;
    const int ch = blockIdx.x >> 2;
    const int R = nrows[b], C = ncols[b];
    const int lane = threadIdx.x & 63, wv = threadIdx.x >> 6;
    const int m = mt * 256 + lane * 4;
    const int n0 = ch * CROWS;
    const int nend = min(R, n0 + CROWS);
    const size_t base = (size_t)b * N_DIM * M_DIM;

    float4 acc = make_float4(0.f, 0.f, 0.f, 0.f);
    if (mt * 256 < C) {
        for (int n = n0 + wv; n < nend; n += 4) {
            float4 v = *(const float4*)(s + base + (size_t)n * M_DIM + m);
            v.x = (m + 0 < C) ? v.x + EPS : 0.f;
            v.y = (m + 1 < C) ? v.y + EPS : 0.f;
            v.z = (m + 2 < C) ? v.z + EPS : 0.f;
            v.w = (m + 3 < C) ? v.w + EPS : 0.f;
            acc.x += v.x; acc.y += v.y; acc.z += v.z; acc.w += v.w;
            union { __half2 h2[2]; uint2 u2; } pk;
            pk.h2[0] = __floats2half2_rn(v.x, v.y);
            pk.h2[1] = __floats2half2_rn(v.z, v.w);
            *(uint2*)(h + base + (size_t)n * M_DIM + m) = pk.u2;
        }
    } else {
        const uint2 z = make_uint2(0u, 0u);
        for (int n = n0 + wv; n < nend; n += 4)
            *(uint2*)(h + base + (size_t)n * M_DIM + m) = z;
    }
    __shared__ float4 red[4][64];
    red[wv][lane] = acc;
    __syncthreads();
    if (wv == 0) {
        float4 a0 = red[0][lane], a1 = red[1][lane],
               a2 = red[2][lane], a3 = red[3][lane];
        float4 t = make_float4(a0.x + a1.x + a2.x + a3.x,
                               a0.y + a1.y + a2.y + a3.y,
                               a0.z + a1.z + a2.z + a3.z,
                               a0.w + a1.w + a2.w + a3.w);
        *(float4*)(tpart + (size_t)(ch * BATCH + b) * M_DIM + m) = t;
    }
}

// col sweep on h (iters 2,4,6,8). grid (2 mt * CH, B): 64-row x 512-col blocks.
__global__ __launch_bounds__(256)
void col_h(const __half* __restrict__ h,
           const int* __restrict__ nrows,
           const int* __restrict__ ncols,
           const float* __restrict__ u,
           float* __restrict__ tpart) {
    const int b  = blockIdx.y;
    const int mt = blockIdx.x & 1;
    const int ch = blockIdx.x >> 1;
    const int R = nrows[b], C = ncols[b];
    const int lane = threadIdx.x & 63, wv = threadIdx.x >> 6;
    const int m = mt * 512 + lane * 8;
    const int n0 = ch * CROWS;
    const int nend = min(R, n0 + CROWS);
    const size_t base = (size_t)b * N_DIM * M_DIM;

    __shared__ float rlds[CROWS];
    if (threadIdx.x < CROWS) {
        float uu = u[b * N_DIM + n0 + threadIdx.x];
        rlds[threadIdx.x] = (uu == 0.f) ? 1.f : 1.f / uu;
    }
    __syncthreads();

    float acc[8] = {0.f, 0.f, 0.f, 0.f, 0.f, 0.f, 0.f, 0.f};
    if (mt * 512 < C) {
        for (int n = n0 + wv; n < nend; n += 4) {
            uint4 raw = *(const uint4*)(h + base + (size_t)n * M_DIM + m);
            const float rn = rlds[n - n0];
            const __half2* hp = (const __half2*)&raw;
#pragma unroll
            for (int k = 0; k < 4; ++k) {
                float2 f = __half22float2(hp[k]);
                acc[2 * k]     += rn * f.x;
                acc[2 * k + 1] += rn * f.y;
            }
        }
    }
    __shared__ float red[4][64 * 8];
#pragma unroll
    for (int k = 0; k < 8; ++k) red[wv][lane * 8 + k] = acc[k];
    __syncthreads();
    if (wv == 0) {
        float t[8];
#pragma unroll
        for (int k = 0; k < 8; ++k)
            t[k] = red[0][lane * 8 + k] + red[1][lane * 8 + k] +
                   red[2][lane * 8 + k] + red[3][lane * 8 + k];
        float* tp = tpart + (size_t)(ch * BATCH + b) * M_DIM + m;
        *(float4*)tp       = make_float4(t[0], t[1], t[2], t[3]);
        *(float4*)(tp + 4) = make_float4(t[4], t[5], t[6], t[7]);
    }
}

// row sweep on h (iters 1,3,5,7,9). grid (32, B): 32 rows/block, 8/wave.
template <bool WRITE_C>
__global__ __launch_bounds__(256)
void row_h(const __half* __restrict__ h,
           const int* __restrict__ nrows,
           const int* __restrict__ ncols,
           const float* __restrict__ tpart,
           float* __restrict__ u,
           float* __restrict__ cOut) {
    const int b = blockIdx.y;
    const int R = nrows[b], C = ncols[b];
    const int n0 = blockIdx.x * 32;
    if (n0 >= R) return;
    const size_t base = (size_t)b * N_DIM * M_DIM;

    __shared__ float clds[M_DIM];
    {
        const int t4 = threadIdx.x * 4;
        float4 sum = make_float4(0.f, 0.f, 0.f, 0.f);
#pragma unroll
        for (int ch = 0; ch < CH; ++ch) {
            float4 p = *(const float4*)(tpart + (size_t)(ch * BATCH + b) * M_DIM + t4);
            sum.x += p.x; sum.y += p.y; sum.z += p.z; sum.w += p.w;
        }
        float4 cv;
        cv.x = (sum.x == 0.f) ? 1.f : 1.f / sum.x;
        cv.y = (sum.y == 0.f) ? 1.f : 1.f / sum.y;
        cv.z = (sum.z == 0.f) ? 1.f : 1.f / sum.z;
        cv.w = (sum.w == 0.f) ? 1.f : 1.f / sum.w;
        *(float4*)&clds[t4] = cv;
        if (WRITE_C && blockIdx.x == 0)
            *(float4*)(cOut + b * M_DIM + t4) = cv;
    }
    __syncthreads();

    const int lane = threadIdx.x & 63, wv = threadIdx.x >> 6;
    const bool hi = (C > 512);           // cols 512..1023 are zero otherwise
#pragma unroll 2
    for (int i = 0; i < 8; ++i) {
        const int n = n0 + wv * 8 + i;
        if (n >= R) break;
        const __half* hrow = h + base + (size_t)n * M_DIM;
        float sum = 0.f;
        {
            uint4 raw = *(const uint4*)(hrow + lane * 8);
            const __half2* hp = (const __half2*)&raw;
            const float* cl = &clds[lane * 8];
#pragma unroll
            for (int k = 0; k < 4; ++k) {
                float2 f = __half22float2(hp[k]);
                sum += f.x * cl[2 * k] + f.y * cl[2 * k + 1];
            }
        }
        if (hi) {
            uint4 raw = *(const uint4*)(hrow + 512 + lane * 8);
            const __half2* hp = (const __half2*)&raw;
            const float* cl = &clds[512 + lane * 8];
#pragma unroll
            for (int k = 0; k < 4; ++k) {
                float2 f = __half22float2(hp[k]);
                sum += f.x * cl[2 * k] + f.y * cl[2 * k + 1];
            }
        }
#pragma unroll
        for (int off = 32; off; off >>= 1) sum += __shfl_down(sum, off);
        if (lane == 0) u[b * N_DIM + n] = sum;
    }
}

// finalize on f32 s (fp16 never touches the output numerator).
__global__ __launch_bounds__(256)
void finalize(const float* __restrict__ s,
              const int* __restrict__ nrows,
              const int* __restrict__ ncols,
              const float* __restrict__ u,
              const float* __restrict__ c,
              float* __restrict__ out) {
    const int n = blockIdx.x;
    const int b = blockIdx.y;
    const int R = nrows[b], C = ncols[b];
    const size_t base = ((size_t)b * N_DIM + n) * M_DIM;
    const int m = threadIdx.x * 4;

    float4 o = make_float4(0.f, 0.f, 0.f, 0.f);
    if (n < R && m < C) {
        float uu = u[b * N_DIM + n];
        float rn = (uu == 0.f) ? 1.f : 1.f / uu;
        float4 v  = *(const float4*)(s + base + m);
        float4 cc = *(const float4*)(c + b * M_DIM + m);
        o.x = (m + 0 < C) ? (v.x + EPS) * rn * cc.x : 0.f;
        o.y = (m + 1 < C) ? (v.y + EPS) * rn * cc.y : 0.f;
        o.z = (m + 2 < C) ? (v.z + EPS) * rn * cc.z : 0.f;
        o.w = (m + 3 < C) ? (v.w + EPS) * rn * cc.w : 0.f;
    }
    *(float4*)(out + base + m) = o;
}

// ===========================================================================
// f32 fallback for small ws (round-3 kernels, unchanged)
// ===========================================================================
template <bool FIRST, int CHUNKS>
__global__ __launch_bounds__(256)
void col_sweep(const float* __restrict__ s, const int* __restrict__ nrows,
               const int* __restrict__ ncols, const float* __restrict__ u,
               float* __restrict__ tpart) {
    const int b  = blockIdx.y;
    const int mt = blockIdx.x & 3;
    const int ch = blockIdx.x >> 2;
    const int R = nrows[b], C = ncols[b];
    const int lane = threadIdx.x & 63, wv = threadIdx.x >> 6;
    const int m0 = mt * 256;
    const int m  = m0 + lane * 4;
    constexpr int RW = N_DIM / CHUNKS;
    const int n0 = ch * RW;
    const int nend = min(R, n0 + RW);

    __shared__ float rlds[RW > 1024 ? 1 : RW];
    if (!FIRST) {
        for (int i = threadIdx.x; i < RW; i += 256) {
            float uu = u[b * N_DIM + n0 + i];
            rlds[i] = (uu == 0.f) ? 1.f : 1.f / uu;
        }
        __syncthreads();
    }
    float4 acc = make_float4(0.f, 0.f, 0.f, 0.f);
    if (m0 < C) {
        const float* __restrict__ sb = s + (size_t)b * N_DIM * M_DIM;
#pragma unroll 4
        for (int n = n0 + wv; n < nend; n += 4) {
            float4 v = *(const float4*)(sb + (size_t)n * M_DIM + m);
            float rn = FIRST ? 1.f : rlds[n - n0];
            acc.x += rn * (v.x + EPS); acc.y += rn * (v.y + EPS);
            acc.z += rn * (v.z + EPS); acc.w += rn * (v.w + EPS);
        }
    }
    __shared__ float4 red[4][64];
    red[wv][lane] = acc;
    __syncthreads();
    if (wv == 0) {
        float4 a0 = red[0][lane], a1 = red[1][lane],
               a2 = red[2][lane], a3 = red[3][lane];
        float4 t = make_float4(a0.x + a1.x + a2.x + a3.x, a0.y + a1.y + a2.y + a3.y,
                               a0.z + a1.z + a2.z + a3.z, a0.w + a1.w + a2.w + a3.w);
        *(float4*)(tpart + ((size_t)(ch * BATCH + b)) * M_DIM + m) = t;
    }
}

template <int CHUNKS, bool WRITE_C>
__global__ __launch_bounds__(256)
void row_sweep(const float* __restrict__ s, const int* __restrict__ nrows,
               const int* __restrict__ ncols, const float* __restrict__ tpart,
               float* __restrict__ u, float* __restrict__ cOut) {
    const int b = blockIdx.y;
    const int R = nrows[b], C = ncols[b];
    const int n0 = blockIdx.x * 16;
    if (n0 >= R) return;
    __shared__ float clds[M_DIM];
    {
        const int t4 = threadIdx.x;
        float4 sum = make_float4(0.f, 0.f, 0.f, 0.f);
#pragma unroll
        for (int ch = 0; ch < CHUNKS; ++ch) {
            float4 p = *(const float4*)(tpart + ((size_t)(ch * BATCH + b)) * M_DIM + t4 * 4);
            sum.x += p.x; sum.y += p.y; sum.z += p.z; sum.w += p.w;
        }
        float4 cv;
        cv.x = (sum.x == 0.f) ? 1.f : 1.f / sum.x;
        cv.y = (sum.y == 0.f) ? 1.f : 1.f / sum.y;
        cv.z = (sum.z == 0.f) ? 1.f : 1.f / sum.z;
        cv.w = (sum.w == 0.f) ? 1.f : 1.f / sum.w;
        *(float4*)&clds[t4 * 4] = cv;
        if (WRITE_C && blockIdx.x == 0)
            *(float4*)(cOut + b * M_DIM + t4 * 4) = cv;
    }
    __syncthreads();
    const int lane = threadIdx.x & 63, wv = threadIdx.x >> 6;
    const int C4 = C >> 2;
#pragma unroll
    for (int i = 0; i < 4; ++i) {
        const int n = n0 + wv * 4 + i;
        if (n >= R) break;
        const float* __restrict__ srow = s + ((size_t)b * N_DIM + n) * M_DIM;
        float sum = 0.f;
        for (int j = lane; j < C4; j += 64) {
            float4 v  = ((const float4*)srow)[j];
            float4 cc = *(const float4*)&clds[j * 4];
            sum += (v.x + EPS) * cc.x + (v.y + EPS) * cc.y +
                   (v.z + EPS) * cc.z + (v.w + EPS) * cc.w;
        }
        for (int mm = (C4 << 2) + lane; mm < C; mm += 64)
            sum += (srow[mm] + EPS) * clds[mm];
#pragma unroll
        for (int off = 32; off; off >>= 1) sum += __shfl_down(sum, off);
        if (lane == 0) u[b * N_DIM + n] = sum;
    }
}

// ===========================================================================
extern "C" void kernel_launch(void* const* d_in, const int* in_sizes, int n_in,
                              void* d_out, int out_size, void* d_ws, size_t ws_size,
                              hipStream_t stream) {
    const float* s     = (const float*)d_in[0];
    const int*   nrows = (const int*)d_in[1];
    const int*   ncols = (const int*)d_in[2];
    float*       out   = (float*)d_out;

    const size_t hElems   = (size_t)BATCH * N_DIM * M_DIM;
    const size_t need_f16 = hElems * 2 +
                            ((size_t)CH * BATCH * M_DIM + BATCH * N_DIM + BATCH * M_DIM) * 4;

    if (ws_size >= need_f16) {
        __half* h     = (__half*)d_ws;
        float*  tpart = (float*)(h + hElems);
        float*  u     = tpart + (size_t)CH * BATCH * M_DIM;
        float*  c     = u + (size_t)BATCH * N_DIM;

        dim3 colGrid1(4 * CH, BATCH);   // conversion sweep: 4096 blocks
        dim3 colGridH(2 * CH, BATCH);   // fp16 col sweep:   2048 blocks
        dim3 rowGridH(32, BATCH);       // fp16 row sweep:   2048 blocks

        col_first_conv<<<colGrid1, 256, 0, stream>>>(s, nrows, ncols, h, tpart);   // i=0
        row_h<false><<<rowGridH, 256, 0, stream>>>(h, nrows, ncols, tpart, u, c);  // i=1
        for (int k = 0; k < 3; ++k) {                                              // i=2..7
            col_h<<<colGridH, 256, 0, stream>>>(h, nrows, ncols, u, tpart);
            row_h<false><<<rowGridH, 256, 0, stream>>>(h, nrows, ncols, tpart, u, c);
        }
        col_h<<<colGridH, 256, 0, stream>>>(h, nrows, ncols, u, tpart);            // i=8
        row_h<true><<<rowGridH, 256, 0, stream>>>(h, nrows, ncols, tpart, u, c);   // i=9
        finalize<<<dim3(N_DIM, BATCH), 256, 0, stream>>>(s, nrows, ncols, u, c, out);
        return;
    }

    // f32 fallback
    const size_t need4 = (size_t)(4 * BATCH * M_DIM + BATCH * N_DIM + BATCH * M_DIM) * 4;
    if (ws_size >= need4) {
        float* tpart = (float*)d_ws;
        float* u = tpart + (size_t)4 * BATCH * M_DIM;
        float* c = u + (size_t)BATCH * N_DIM;
        dim3 colGrid(16, BATCH), rowGrid(64, BATCH);
        col_sweep<true, 4><<<colGrid, 256, 0, stream>>>(s, nrows, ncols, u, tpart);
        row_sweep<4, false><<<rowGrid, 256, 0, stream>>>(s, nrows, ncols, tpart, u, c);
        for (int k = 1; k < 4; ++k) {
            col_sweep<false, 4><<<colGrid, 256, 0, stream>>>(s, nrows, ncols, u, tpart);
            row_sweep<4, false><<<rowGrid, 256, 0, stream>>>(s, nrows, ncols, tpart, u, c);
        }
        col_sweep<false, 4><<<colGrid, 256, 0, stream>>>(s, nrows, ncols, u, tpart);
        row_sweep<4, true><<<rowGrid, 256, 0, stream>>>(s, nrows, ncols, tpart, u, c);
        finalize<<<dim3(N_DIM, BATCH), 256, 0, stream>>>(s, nrows, ncols, u, c, out);
    } else {
        float* tpart = (float*)d_ws;
        float* u = tpart + (size_t)BATCH * M_DIM;
        float* c = u + (size_t)BATCH * N_DIM;
        dim3 colGrid(4, BATCH), rowGrid(64, BATCH);
        col_sweep<true, 1><<<colGrid, 256, 0, stream>>>(s, nrows, ncols, u, tpart);
        row_sweep<1, false><<<rowGrid, 256, 0, stream>>>(s, nrows, ncols, tpart, u, c);
        for (int k = 1; k < 4; ++k) {
            col_sweep<false, 1><<<colGrid, 256, 0, stream>>>(s, nrows, ncols, u, tpart);
            row_sweep<1, false><<<rowGrid, 256, 0, stream>>>(s, nrows, ncols, tpart, u, c);
        }
        col_sweep<false, 1><<<colGrid, 256, 0, stream>>>(s, nrows, ncols, u, tpart);
        row_sweep<1, true><<<rowGrid, 256, 0, stream>>>(s, nrows, ncols, tpart, u, c);
        finalize<<<dim3(N_DIM, BATCH), 256, 0, stream>>>(s, nrows, ncols, u, c, out);
    }
}

// Round 6
// 235.007 us; speedup vs baseline: 1.1386x; 1.0171x over previous
//
#include <hip/hip_runtime.h>
#include <hip/hip_fp16.h>

#define EPS 1e-4f
constexpr int N_DIM = 1024;
constexpr int M_DIM = 1024;
constexpr int BATCH = 64;
constexpr int CH    = 8;              // n-chunks for col partials
constexpr int CROWS = N_DIM / CH;     // 128 rows per chunk

// Factor form: out = r[n]*(s+EPS)*c[m]; sweeps alternate
//   col: traw[m] = sum_{n<R} r[n]*(s+EPS),  r = 1/uraw
//   row: uraw[n] = sum_{m<C} c[m]*(s+EPS),  c = 1/traw
// fp16 path: iter0 converts h = fp16(s+EPS) (0 beyond C, rows<R only);
// iters 1..9 sweep h; iter 9 fused with the output write (out = h*r*c, so
// h==0 beyond C and the n>=R guard give the zero-masking for free).

// ===========================================================================
// fp16 fast path
// ===========================================================================

// iter 0 (col, r==1) fused with conversion. grid (4 mt * CH, B), 256 thr.
__global__ __launch_bounds__(256)
void col_first_conv(const float* __restrict__ s,
                    const int* __restrict__ nrows,
                    const int* __restrict__ ncols,
                    __half* __restrict__ h,
                    float* __restrict__ tpart) {
    const int b  = blockIdx.y;
    const int mt = blockIdx.x & 3;
    const int ch = blockIdx.x >> 2;
    const int R = nrows[b], C = ncols[b];
    const int lane = threadIdx.x & 63, wv = threadIdx.x >> 6;
    const int m = mt * 256 + lane * 4;
    const int n0 = ch * CROWS;
    const int nend = min(R, n0 + CROWS);
    const size_t base = (size_t)b * N_DIM * M_DIM;

    float4 acc = make_float4(0.f, 0.f, 0.f, 0.f);
    if (mt * 256 < C) {
        for (int n = n0 + wv; n < nend; n += 4) {
            float4 v = *(const float4*)(s + base + (size_t)n * M_DIM + m);
            v.x = (m + 0 < C) ? v.x + EPS : 0.f;
            v.y = (m + 1 < C) ? v.y + EPS : 0.f;
            v.z = (m + 2 < C) ? v.z + EPS : 0.f;
            v.w = (m + 3 < C) ? v.w + EPS : 0.f;
            acc.x += v.x; acc.y += v.y; acc.z += v.z; acc.w += v.w;
            union { __half2 h2[2]; uint2 u2; } pk;
            pk.h2[0] = __floats2half2_rn(v.x, v.y);
            pk.h2[1] = __floats2half2_rn(v.z, v.w);
            *(uint2*)(h + base + (size_t)n * M_DIM + m) = pk.u2;
        }
    } else {
        const uint2 z = make_uint2(0u, 0u);
        for (int n = n0 + wv; n < nend; n += 4)
            *(uint2*)(h + base + (size_t)n * M_DIM + m) = z;
    }
    __shared__ float4 red[4][64];
    red[wv][lane] = acc;
    __syncthreads();
    if (wv == 0) {
        float4 a0 = red[0][lane], a1 = red[1][lane],
               a2 = red[2][lane], a3 = red[3][lane];
        float4 t = make_float4(a0.x + a1.x + a2.x + a3.x,
                               a0.y + a1.y + a2.y + a3.y,
                               a0.z + a1.z + a2.z + a3.z,
                               a0.w + a1.w + a2.w + a3.w);
        *(float4*)(tpart + (size_t)(ch * BATCH + b) * M_DIM + m) = t;
    }
}

// col sweep on h (iters 2,4,6,8). grid (2 mt * CH, B): 128-row x 512-col blocks.
__global__ __launch_bounds__(256)
void col_h(const __half* __restrict__ h,
           const int* __restrict__ nrows,
           const int* __restrict__ ncols,
           const float* __restrict__ u,
           float* __restrict__ tpart) {
    const int b  = blockIdx.y;
    const int mt = blockIdx.x & 1;
    const int ch = blockIdx.x >> 1;
    const int R = nrows[b], C = ncols[b];
    const int lane = threadIdx.x & 63, wv = threadIdx.x >> 6;
    const int m = mt * 512 + lane * 8;
    const int n0 = ch * CROWS;
    const int nend = min(R, n0 + CROWS);
    const size_t base = (size_t)b * N_DIM * M_DIM;

    __shared__ float rlds[CROWS];
    for (int i = threadIdx.x; i < CROWS; i += 256) {
        float uu = u[b * N_DIM + n0 + i];
        rlds[i] = (uu == 0.f) ? 1.f : 1.f / uu;
    }
    __syncthreads();

    float acc[8] = {0.f, 0.f, 0.f, 0.f, 0.f, 0.f, 0.f, 0.f};
    if (mt * 512 < C) {
        for (int n = n0 + wv; n < nend; n += 4) {
            uint4 raw = *(const uint4*)(h + base + (size_t)n * M_DIM + m);
            const float rn = rlds[n - n0];
            const __half2* hp = (const __half2*)&raw;
#pragma unroll
            for (int k = 0; k < 4; ++k) {
                float2 f = __half22float2(hp[k]);
                acc[2 * k]     += rn * f.x;
                acc[2 * k + 1] += rn * f.y;
            }
        }
    }
    __shared__ float red[4][64 * 8];
#pragma unroll
    for (int k = 0; k < 8; ++k) red[wv][lane * 8 + k] = acc[k];
    __syncthreads();
    if (wv == 0) {
        float t[8];
#pragma unroll
        for (int k = 0; k < 8; ++k)
            t[k] = red[0][lane * 8 + k] + red[1][lane * 8 + k] +
                   red[2][lane * 8 + k] + red[3][lane * 8 + k];
        float* tp = tpart + (size_t)(ch * BATCH + b) * M_DIM + m;
        *(float4*)tp       = make_float4(t[0], t[1], t[2], t[3]);
        *(float4*)(tp + 4) = make_float4(t[4], t[5], t[6], t[7]);
    }
}

// row sweep on h (iters 1,3,5,7). grid (32, B): 32 rows/block, 8/wave.
__global__ __launch_bounds__(256)
void row_h(const __half* __restrict__ h,
           const int* __restrict__ nrows,
           const int* __restrict__ ncols,
           const float* __restrict__ tpart,
           float* __restrict__ u) {
    const int b = blockIdx.y;
    const int R = nrows[b], C = ncols[b];
    const int n0 = blockIdx.x * 32;
    if (n0 >= R) return;
    const size_t base = (size_t)b * N_DIM * M_DIM;

    __shared__ float clds[M_DIM];
    {
        const int t4 = threadIdx.x * 4;
        float4 sum = make_float4(0.f, 0.f, 0.f, 0.f);
#pragma unroll
        for (int ch = 0; ch < CH; ++ch) {
            float4 p = *(const float4*)(tpart + (size_t)(ch * BATCH + b) * M_DIM + t4);
            sum.x += p.x; sum.y += p.y; sum.z += p.z; sum.w += p.w;
        }
        float4 cv;
        cv.x = (sum.x == 0.f) ? 1.f : 1.f / sum.x;
        cv.y = (sum.y == 0.f) ? 1.f : 1.f / sum.y;
        cv.z = (sum.z == 0.f) ? 1.f : 1.f / sum.z;
        cv.w = (sum.w == 0.f) ? 1.f : 1.f / sum.w;
        *(float4*)&clds[t4] = cv;
    }
    __syncthreads();

    const int lane = threadIdx.x & 63, wv = threadIdx.x >> 6;
    const bool hi = (C > 512);           // cols 512..1023 are zero otherwise
#pragma unroll 2
    for (int i = 0; i < 8; ++i) {
        const int n = n0 + wv * 8 + i;
        if (n >= R) break;
        const __half* hrow = h + base + (size_t)n * M_DIM;
        float sum = 0.f;
        {
            uint4 raw = *(const uint4*)(hrow + lane * 8);
            const __half2* hp = (const __half2*)&raw;
            const float* cl = &clds[lane * 8];
#pragma unroll
            for (int k = 0; k < 4; ++k) {
                float2 f = __half22float2(hp[k]);
                sum += f.x * cl[2 * k] + f.y * cl[2 * k + 1];
            }
        }
        if (hi) {
            uint4 raw = *(const uint4*)(hrow + 512 + lane * 8);
            const __half2* hp = (const __half2*)&raw;
            const float* cl = &clds[512 + lane * 8];
#pragma unroll
            for (int k = 0; k < 4; ++k) {
                float2 f = __half22float2(hp[k]);
                sum += f.x * cl[2 * k] + f.y * cl[2 * k + 1];
            }
        }
#pragma unroll
        for (int off = 32; off; off >>= 1) sum += __shfl_down(sum, off);
        if (lane == 0) u[b * N_DIM + n] = sum;
    }
}

// iter 9 row sweep fused with output write. grid (32, B) covering ALL rows.
// out[n][m] = (n<R) ? h[n][m] * (1/u[n]) * c[m] : 0   (h==0 for m>=C).
__global__ __launch_bounds__(256)
void row_final(const __half* __restrict__ h,
               const int* __restrict__ nrows,
               const int* __restrict__ ncols,
               const float* __restrict__ tpart,
               float* __restrict__ out) {
    const int b = blockIdx.y;
    const int R = nrows[b], C = ncols[b];
    const int n0 = blockIdx.x * 32;
    const size_t base = (size_t)b * N_DIM * M_DIM;

    __shared__ float clds[M_DIM];
    {
        const int t4 = threadIdx.x * 4;
        float4 sum = make_float4(0.f, 0.f, 0.f, 0.f);
#pragma unroll
        for (int ch = 0; ch < CH; ++ch) {
            float4 p = *(const float4*)(tpart + (size_t)(ch * BATCH + b) * M_DIM + t4);
            sum.x += p.x; sum.y += p.y; sum.z += p.z; sum.w += p.w;
        }
        float4 cv;
        cv.x = (sum.x == 0.f) ? 1.f : 1.f / sum.x;
        cv.y = (sum.y == 0.f) ? 1.f : 1.f / sum.y;
        cv.z = (sum.z == 0.f) ? 1.f : 1.f / sum.z;
        cv.w = (sum.w == 0.f) ? 1.f : 1.f / sum.w;
        *(float4*)&clds[t4] = cv;
    }
    __syncthreads();

    const int lane = threadIdx.x & 63, wv = threadIdx.x >> 6;
    const bool hi = (C > 512);
    const float4 z4 = make_float4(0.f, 0.f, 0.f, 0.f);

    for (int i = 0; i < 8; ++i) {
        const int n = n0 + wv * 8 + i;
        float* orow = out + base + (size_t)n * M_DIM;
        float4 o0 = z4, o1 = z4, o2 = z4, o3 = z4;
        if (n < R) {
            const __half* hrow = h + base + (size_t)n * M_DIM;
            uint4 rlo = *(const uint4*)(hrow + lane * 8);
            uint4 rhi;
            float flo[8], fhi[8];
            const __half2* hp = (const __half2*)&rlo;
#pragma unroll
            for (int k = 0; k < 4; ++k) {
                float2 f = __half22float2(hp[k]);
                flo[2 * k] = f.x; flo[2 * k + 1] = f.y;
            }
            const float* cl = &clds[lane * 8];
            float sum = 0.f;
#pragma unroll
            for (int k = 0; k < 8; ++k) sum += flo[k] * cl[k];
            if (hi) {
                rhi = *(const uint4*)(hrow + 512 + lane * 8);
                const __half2* hq = (const __half2*)&rhi;
#pragma unroll
                for (int k = 0; k < 4; ++k) {
                    float2 f = __half22float2(hq[k]);
                    fhi[2 * k] = f.x; fhi[2 * k + 1] = f.y;
                }
                const float* ch2 = &clds[512 + lane * 8];
#pragma unroll
                for (int k = 0; k < 8; ++k) sum += fhi[k] * ch2[k];
            }
#pragma unroll
            for (int off = 32; off; off >>= 1) sum += __shfl_down(sum, off);
            float tot = __shfl(sum, 0);
            const float rn = (tot == 0.f) ? 1.f : 1.f / tot;

            o0 = make_float4(flo[0] * rn * cl[0], flo[1] * rn * cl[1],
                             flo[2] * rn * cl[2], flo[3] * rn * cl[3]);
            o1 = make_float4(flo[4] * rn * cl[4], flo[5] * rn * cl[5],
                             flo[6] * rn * cl[6], flo[7] * rn * cl[7]);
            if (hi) {
                const float* ch2 = &clds[512 + lane * 8];
                o2 = make_float4(fhi[0] * rn * ch2[0], fhi[1] * rn * ch2[1],
                                 fhi[2] * rn * ch2[2], fhi[3] * rn * ch2[3]);
                o3 = make_float4(fhi[4] * rn * ch2[4], fhi[5] * rn * ch2[5],
                                 fhi[6] * rn * ch2[6], fhi[7] * rn * ch2[7]);
            }
        }
        *(float4*)(orow + lane * 8)           = o0;
        *(float4*)(orow + lane * 8 + 4)       = o1;
        *(float4*)(orow + 512 + lane * 8)     = o2;
        *(float4*)(orow + 512 + lane * 8 + 4) = o3;
    }
}

// ===========================================================================
// f32 fallback for small ws (round-3 kernels, unchanged)
// ===========================================================================
template <bool FIRST, int CHUNKS>
__global__ __launch_bounds__(256)
void col_sweep(const float* __restrict__ s, const int* __restrict__ nrows,
               const int* __restrict__ ncols, const float* __restrict__ u,
               float* __restrict__ tpart) {
    const int b  = blockIdx.y;
    const int mt = blockIdx.x & 3;
    const int ch = blockIdx.x >> 2;
    const int R = nrows[b], C = ncols[b];
    const int lane = threadIdx.x & 63, wv = threadIdx.x >> 6;
    const int m0 = mt * 256;
    const int m  = m0 + lane * 4;
    constexpr int RW = N_DIM / CHUNKS;
    const int n0 = ch * RW;
    const int nend = min(R, n0 + RW);

    __shared__ float rlds[RW > 1024 ? 1 : RW];
    if (!FIRST) {
        for (int i = threadIdx.x; i < RW; i += 256) {
            float uu = u[b * N_DIM + n0 + i];
            rlds[i] = (uu == 0.f) ? 1.f : 1.f / uu;
        }
        __syncthreads();
    }
    float4 acc = make_float4(0.f, 0.f, 0.f, 0.f);
    if (m0 < C) {
        const float* __restrict__ sb = s + (size_t)b * N_DIM * M_DIM;
#pragma unroll 4
        for (int n = n0 + wv; n < nend; n += 4) {
            float4 v = *(const float4*)(sb + (size_t)n * M_DIM + m);
            float rn = FIRST ? 1.f : rlds[n - n0];
            acc.x += rn * (v.x + EPS); acc.y += rn * (v.y + EPS);
            acc.z += rn * (v.z + EPS); acc.w += rn * (v.w + EPS);
        }
    }
    __shared__ float4 red[4][64];
    red[wv][lane] = acc;
    __syncthreads();
    if (wv == 0) {
        float4 a0 = red[0][lane], a1 = red[1][lane],
               a2 = red[2][lane], a3 = red[3][lane];
        float4 t = make_float4(a0.x + a1.x + a2.x + a3.x, a0.y + a1.y + a2.y + a3.y,
                               a0.z + a1.z + a2.z + a3.z, a0.w + a1.w + a2.w + a3.w);
        *(float4*)(tpart + ((size_t)(ch * BATCH + b)) * M_DIM + m) = t;
    }
}

template <int CHUNKS, bool WRITE_C>
__global__ __launch_bounds__(256)
void row_sweep(const float* __restrict__ s, const int* __restrict__ nrows,
               const int* __restrict__ ncols, const float* __restrict__ tpart,
               float* __restrict__ u, float* __restrict__ cOut) {
    const int b = blockIdx.y;
    const int R = nrows[b], C = ncols[b];
    const int n0 = blockIdx.x * 16;
    if (n0 >= R) return;
    __shared__ float clds[M_DIM];
    {
        const int t4 = threadIdx.x;
        float4 sum = make_float4(0.f, 0.f, 0.f, 0.f);
#pragma unroll
        for (int ch = 0; ch < CHUNKS; ++ch) {
            float4 p = *(const float4*)(tpart + ((size_t)(ch * BATCH + b)) * M_DIM + t4 * 4);
            sum.x += p.x; sum.y += p.y; sum.z += p.z; sum.w += p.w;
        }
        float4 cv;
        cv.x = (sum.x == 0.f) ? 1.f : 1.f / sum.x;
        cv.y = (sum.y == 0.f) ? 1.f : 1.f / sum.y;
        cv.z = (sum.z == 0.f) ? 1.f : 1.f / sum.z;
        cv.w = (sum.w == 0.f) ? 1.f : 1.f / sum.w;
        *(float4*)&clds[t4 * 4] = cv;
        if (WRITE_C && blockIdx.x == 0)
            *(float4*)(cOut + b * M_DIM + t4 * 4) = cv;
    }
    __syncthreads();
    const int lane = threadIdx.x & 63, wv = threadIdx.x >> 6;
    const int C4 = C >> 2;
#pragma unroll
    for (int i = 0; i < 4; ++i) {
        const int n = n0 + wv * 4 + i;
        if (n >= R) break;
        const float* __restrict__ srow = s + ((size_t)b * N_DIM + n) * M_DIM;
        float sum = 0.f;
        for (int j = lane; j < C4; j += 64) {
            float4 v  = ((const float4*)srow)[j];
            float4 cc = *(const float4*)&clds[j * 4];
            sum += (v.x + EPS) * cc.x + (v.y + EPS) * cc.y +
                   (v.z + EPS) * cc.z + (v.w + EPS) * cc.w;
        }
        for (int mm = (C4 << 2) + lane; mm < C; mm += 64)
            sum += (srow[mm] + EPS) * clds[mm];
#pragma unroll
        for (int off = 32; off; off >>= 1) sum += __shfl_down(sum, off);
        if (lane == 0) u[b * N_DIM + n] = sum;
    }
}

__global__ __launch_bounds__(256)
void finalize(const float* __restrict__ s, const int* __restrict__ nrows,
              const int* __restrict__ ncols, const float* __restrict__ u,
              const float* __restrict__ c, float* __restrict__ out) {
    const int n = blockIdx.x;
    const int b = blockIdx.y;
    const int R = nrows[b], C = ncols[b];
    const size_t base = ((size_t)b * N_DIM + n) * M_DIM;
    const int m = threadIdx.x * 4;

    float4 o = make_float4(0.f, 0.f, 0.f, 0.f);
    if (n < R && m < C) {
        float uu = u[b * N_DIM + n];
        float rn = (uu == 0.f) ? 1.f : 1.f / uu;
        float4 v  = *(const float4*)(s + base + m);
        float4 cc = *(const float4*)(c + b * M_DIM + m);
        o.x = (m + 0 < C) ? (v.x + EPS) * rn * cc.x : 0.f;
        o.y = (m + 1 < C) ? (v.y + EPS) * rn * cc.y : 0.f;
        o.z = (m + 2 < C) ? (v.z + EPS) * rn * cc.z : 0.f;
        o.w = (m + 3 < C) ? (v.w + EPS) * rn * cc.w : 0.f;
    }
    *(float4*)(out + base + m) = o;
}

// ===========================================================================
extern "C" void kernel_launch(void* const* d_in, const int* in_sizes, int n_in,
                              void* d_out, int out_size, void* d_ws, size_t ws_size,
                              hipStream_t stream) {
    const float* s     = (const float*)d_in[0];
    const int*   nrows = (const int*)d_in[1];
    const int*   ncols = (const int*)d_in[2];
    float*       out   = (float*)d_out;

    const size_t hElems   = (size_t)BATCH * N_DIM * M_DIM;
    const size_t need_f16 = hElems * 2 +
                            ((size_t)CH * BATCH * M_DIM + BATCH * N_DIM) * 4;

    if (ws_size >= need_f16) {
        __half* h     = (__half*)d_ws;
        float*  tpart = (float*)(h + hElems);
        float*  u     = tpart + (size_t)CH * BATCH * M_DIM;

        dim3 colGrid1(4 * CH, BATCH);   // conversion sweep: 2048 blocks
        dim3 colGridH(2 * CH, BATCH);   // fp16 col sweep:   1024 blocks
        dim3 rowGridH(32, BATCH);       // fp16 row sweep:   2048 blocks

        col_first_conv<<<colGrid1, 256, 0, stream>>>(s, nrows, ncols, h, tpart);  // i=0
        row_h<<<rowGridH, 256, 0, stream>>>(h, nrows, ncols, tpart, u);           // i=1
        for (int k = 0; k < 3; ++k) {                                             // i=2..7
            col_h<<<colGridH, 256, 0, stream>>>(h, nrows, ncols, u, tpart);
            row_h<<<rowGridH, 256, 0, stream>>>(h, nrows, ncols, tpart, u);
        }
        col_h<<<colGridH, 256, 0, stream>>>(h, nrows, ncols, u, tpart);           // i=8
        row_final<<<rowGridH, 256, 0, stream>>>(h, nrows, ncols, tpart, out);     // i=9+out
        return;
    }

    // f32 fallback
    const size_t need4 = (size_t)(4 * BATCH * M_DIM + BATCH * N_DIM + BATCH * M_DIM) * 4;
    if (ws_size >= need4) {
        float* tpart = (float*)d_ws;
        float* u = tpart + (size_t)4 * BATCH * M_DIM;
        float* c = u + (size_t)BATCH * N_DIM;
        dim3 colGrid(16, BATCH), rowGrid(64, BATCH);
        col_sweep<true, 4><<<colGrid, 256, 0, stream>>>(s, nrows, ncols, u, tpart);
        row_sweep<4, false><<<rowGrid, 256, 0, stream>>>(s, nrows, ncols, tpart, u, c);
        for (int k = 1; k < 4; ++k) {
            col_sweep<false, 4><<<colGrid, 256, 0, stream>>>(s, nrows, ncols, u, tpart);
            row_sweep<4, false><<<rowGrid, 256, 0, stream>>>(s, nrows, ncols, tpart, u, c);
        }
        col_sweep<false, 4><<<colGrid, 256, 0, stream>>>(s, nrows, ncols, u, tpart);
        row_sweep<4, true><<<rowGrid, 256, 0, stream>>>(s, nrows, ncols, tpart, u, c);
        finalize<<<dim3(N_DIM, BATCH), 256, 0, stream>>>(s, nrows, ncols, u, c, out);
    } else {
        float* tpart = (float*)d_ws;
        float* u = tpart + (size_t)BATCH * M_DIM;
        float* c = u + (size_t)BATCH * N_DIM;
        dim3 colGrid(4, BATCH), rowGrid(64, BATCH);
        col_sweep<true, 1><<<colGrid, 256, 0, stream>>>(s, nrows, ncols, u, tpart);
        row_sweep<1, false><<<rowGrid, 256, 0, stream>>>(s, nrows, ncols, tpart, u, c);
        for (int k = 1; k < 4; ++k) {
            col_sweep<false, 1><<<colGrid, 256, 0, stream>>>(s, nrows, ncols, u, tpart);
            row_sweep<1, false><<<rowGrid, 256, 0, stream>>>(s, nrows, ncols, tpart, u, c);
        }
        col_sweep<false, 1><<<colGrid, 256, 0, stream>>>(s, nrows, ncols, u, tpart);
        row_sweep<1, true><<<rowGrid, 256, 0, stream>>>(s, nrows, ncols, tpart, u, c);
        finalize<<<dim3(N_DIM, BATCH), 256, 0, stream>>>(s, nrows, ncols, u, c, out);
    }
}

// Round 7
// 210.383 us; speedup vs baseline: 1.2718x; 1.1170x over previous
//
#include <hip/hip_runtime.h>
#include <hip/hip_fp16.h>

#define EPS 1e-4f
constexpr int N_DIM = 1024;
constexpr int M_DIM = 1024;
constexpr int BATCH = 64;
constexpr int CH    = 16;             // row chunks == tpart chunks
constexpr int CROWS = N_DIM / CH;     // 64 rows per chunk

// Factor form: out = r[n]*(s+EPS)*c[m].
//   conv   : h = fp16(s+EPS) (cols>=C zeroed, rows<R only) + tpart0[ch][m] = col partials (r==1)
//   K(odd i): c = 1/sum_ch tpartIn ; per row u = <c,h[n]>, r = 1/u ;
//             tpartOut[ch][m] = sum_{n in ch} r[n]*h[n][m]   (same rows -> local r!)
//   K_final : same c,u,r but writes out = r*h*c (zeros for n>=R; h==0 for m>=C).
// 6 dispatches total; tpart ping-pongs between two buffers.

// ---------------------------------------------------------------------------
// conv: grid (4 mt * CH, B), 256 thr = 4 waves.
// ---------------------------------------------------------------------------
__global__ __launch_bounds__(256)
void conv_col0(const float* __restrict__ s,
               const int* __restrict__ nrows,
               const int* __restrict__ ncols,
               __half* __restrict__ h,
               float* __restrict__ tp0) {
    const int b  = blockIdx.y;
    const int mt = blockIdx.x & 3;
    const int ch = blockIdx.x >> 2;
    const int R = nrows[b], C = ncols[b];
    const int n0 = ch * CROWS;
    if (n0 >= R) return;                       // reducer skips empty chunks
    const int lane = threadIdx.x & 63, wv = threadIdx.x >> 6;
    const int m = mt * 256 + lane * 4;
    const int nend = min(R, n0 + CROWS);
    const size_t base = (size_t)b * N_DIM * M_DIM;

    float4 acc = make_float4(0.f, 0.f, 0.f, 0.f);
    if (mt * 256 < C) {
        for (int n = n0 + wv; n < nend; n += 4) {
            float4 v = *(const float4*)(s + base + (size_t)n * M_DIM + m);
            v.x = (m + 0 < C) ? v.x + EPS : 0.f;
            v.y = (m + 1 < C) ? v.y + EPS : 0.f;
            v.z = (m + 2 < C) ? v.z + EPS : 0.f;
            v.w = (m + 3 < C) ? v.w + EPS : 0.f;
            acc.x += v.x; acc.y += v.y; acc.z += v.z; acc.w += v.w;
            union { __half2 h2[2]; uint2 u2; } pk;
            pk.h2[0] = __floats2half2_rn(v.x, v.y);
            pk.h2[1] = __floats2half2_rn(v.z, v.w);
            *(uint2*)(h + base + (size_t)n * M_DIM + m) = pk.u2;
        }
    } else {
        const uint2 z = make_uint2(0u, 0u);
        for (int n = n0 + wv; n < nend; n += 4)
            *(uint2*)(h + base + (size_t)n * M_DIM + m) = z;
    }
    __shared__ float4 red[4][64];
    red[wv][lane] = acc;
    __syncthreads();
    if (wv == 0) {
        float4 a0 = red[0][lane], a1 = red[1][lane],
               a2 = red[2][lane], a3 = red[3][lane];
        float4 t = make_float4(a0.x + a1.x + a2.x + a3.x,
                               a0.y + a1.y + a2.y + a3.y,
                               a0.z + a1.z + a2.z + a3.z,
                               a0.w + a1.w + a2.w + a3.w);
        *(float4*)(tp0 + (size_t)(ch * BATCH + b) * M_DIM + m) = t;
    }
}

// ---------------------------------------------------------------------------
// row step: grid (CH, B), 256 thr = 4 waves x 16 rows.
// Reduces tpIn -> c, computes per-row r, emits tpOut (or the output rows).
// ---------------------------------------------------------------------------
template <bool FINAL>
__global__ __launch_bounds__(256)
void row_step(const __half* __restrict__ h,
              const int* __restrict__ nrows,
              const int* __restrict__ ncols,
              const float* __restrict__ tpIn,
              float* __restrict__ tpOut,
              float* __restrict__ out) {
    const int b  = blockIdx.y;
    const int ch = blockIdx.x;
    const int R = nrows[b], C = ncols[b];
    const int n0 = ch * CROWS;
    if (!FINAL && n0 >= R) return;
    const int lane = threadIdx.x & 63, wv = threadIdx.x >> 6;
    const size_t base = (size_t)b * N_DIM * M_DIM;
    const bool hi = (C > 512);
    const bool anyrows = (n0 < R);

    __shared__ float clds[M_DIM];
    __shared__ float tp_lds[4][M_DIM];

    float crlo[8], crhi[8];
    if (anyrows) {                              // block-uniform
        const int nch = min(CH, (R + CROWS - 1) / CROWS);
        const int t4 = threadIdx.x * 4;
        if (hi || t4 < 512) {
            float4 sum = make_float4(0.f, 0.f, 0.f, 0.f);
            for (int cc = 0; cc < nch; ++cc) {
                float4 p = *(const float4*)(tpIn + (size_t)(cc * BATCH + b) * M_DIM + t4);
                sum.x += p.x; sum.y += p.y; sum.z += p.z; sum.w += p.w;
            }
            float4 cv;
            cv.x = (sum.x == 0.f) ? 1.f : 1.f / sum.x;
            cv.y = (sum.y == 0.f) ? 1.f : 1.f / sum.y;
            cv.z = (sum.z == 0.f) ? 1.f : 1.f / sum.z;
            cv.w = (sum.w == 0.f) ? 1.f : 1.f / sum.w;
            *(float4*)&clds[t4] = cv;
        }
        __syncthreads();
        {
            float4 a = *(const float4*)&clds[lane * 8];
            float4 bb = *(const float4*)&clds[lane * 8 + 4];
            crlo[0]=a.x; crlo[1]=a.y; crlo[2]=a.z; crlo[3]=a.w;
            crlo[4]=bb.x; crlo[5]=bb.y; crlo[6]=bb.z; crlo[7]=bb.w;
            if (hi) {
                float4 d = *(const float4*)&clds[512 + lane * 8];
                float4 e = *(const float4*)&clds[512 + lane * 8 + 4];
                crhi[0]=d.x; crhi[1]=d.y; crhi[2]=d.z; crhi[3]=d.w;
                crhi[4]=e.x; crhi[5]=e.y; crhi[6]=e.z; crhi[7]=e.w;
            }
        }
    }

    float tplo[8] = {0,0,0,0,0,0,0,0};
    float tphi[8] = {0,0,0,0,0,0,0,0};

    for (int i = 0; i < 16; ++i) {
        const int n = n0 + wv * 16 + i;          // wave-uniform
        if (n < R) {
            const __half* hrow = h + base + (size_t)n * M_DIM;
            uint4 rlo = *(const uint4*)(hrow + lane * 8);
            float flo[8];
            {
                const __half2* hp = (const __half2*)&rlo;
#pragma unroll
                for (int k = 0; k < 4; ++k) {
                    float2 f = __half22float2(hp[k]);
                    flo[2*k] = f.x; flo[2*k+1] = f.y;
                }
            }
            float dot = 0.f;
#pragma unroll
            for (int k = 0; k < 8; ++k) dot += flo[k] * crlo[k];
            float fhi[8];
            if (hi) {
                uint4 rhi = *(const uint4*)(hrow + 512 + lane * 8);
                const __half2* hq = (const __half2*)&rhi;
#pragma unroll
                for (int k = 0; k < 4; ++k) {
                    float2 f = __half22float2(hq[k]);
                    fhi[2*k] = f.x; fhi[2*k+1] = f.y;
                }
#pragma unroll
                for (int k = 0; k < 8; ++k) dot += fhi[k] * crhi[k];
            }
#pragma unroll
            for (int off = 32; off; off >>= 1) dot += __shfl_xor(dot, off);
            const float r = (dot == 0.f) ? 1.f : 1.f / dot;

            if (FINAL) {
                float* orow = out + base + (size_t)n * M_DIM;
                float4 o0 = make_float4(flo[0]*r*crlo[0], flo[1]*r*crlo[1],
                                        flo[2]*r*crlo[2], flo[3]*r*crlo[3]);
                float4 o1 = make_float4(flo[4]*r*crlo[4], flo[5]*r*crlo[5],
                                        flo[6]*r*crlo[6], flo[7]*r*crlo[7]);
                *(float4*)(orow + lane * 8)     = o0;
                *(float4*)(orow + lane * 8 + 4) = o1;
                float4 o2 = make_float4(0.f,0.f,0.f,0.f), o3 = o2;
                if (hi) {
                    o2 = make_float4(fhi[0]*r*crhi[0], fhi[1]*r*crhi[1],
                                     fhi[2]*r*crhi[2], fhi[3]*r*crhi[3]);
                    o3 = make_float4(fhi[4]*r*crhi[4], fhi[5]*r*crhi[5],
                                     fhi[6]*r*crhi[6], fhi[7]*r*crhi[7]);
                }
                *(float4*)(orow + 512 + lane * 8)     = o2;
                *(float4*)(orow + 512 + lane * 8 + 4) = o3;
            } else {
#pragma unroll
                for (int k = 0; k < 8; ++k) tplo[k] += flo[k] * r;
                if (hi) {
#pragma unroll
                    for (int k = 0; k < 8; ++k) tphi[k] += fhi[k] * r;
                }
            }
        } else if (FINAL) {
            float* orow = out + base + (size_t)n * M_DIM;
            const float4 z = make_float4(0.f, 0.f, 0.f, 0.f);
            *(float4*)(orow + lane * 8)           = z;
            *(float4*)(orow + lane * 8 + 4)       = z;
            *(float4*)(orow + 512 + lane * 8)     = z;
            *(float4*)(orow + 512 + lane * 8 + 4) = z;
        }
    }

    if (!FINAL) {
#pragma unroll
        for (int k = 0; k < 8; ++k) tp_lds[wv][lane * 8 + k] = tplo[k];
        if (hi) {
#pragma unroll
            for (int k = 0; k < 8; ++k) tp_lds[wv][512 + lane * 8 + k] = tphi[k];
        }
        __syncthreads();
        const int t4 = threadIdx.x * 4;
        if (hi || t4 < 512) {
            float4 s0 = *(const float4*)&tp_lds[0][t4];
            float4 s1 = *(const float4*)&tp_lds[1][t4];
            float4 s2 = *(const float4*)&tp_lds[2][t4];
            float4 s3 = *(const float4*)&tp_lds[3][t4];
            float4 t = make_float4(s0.x+s1.x+s2.x+s3.x, s0.y+s1.y+s2.y+s3.y,
                                   s0.z+s1.z+s2.z+s3.z, s0.w+s1.w+s2.w+s3.w);
            *(float4*)(tpOut + (size_t)(ch * BATCH + b) * M_DIM + t4) = t;
        }
    }
}

// ===========================================================================
// f32 fallback for small ws (round-3 kernels, verified)
// ===========================================================================
template <bool FIRST, int CHUNKS>
__global__ __launch_bounds__(256)
void col_sweep(const float* __restrict__ s, const int* __restrict__ nrows,
               const int* __restrict__ ncols, const float* __restrict__ u,
               float* __restrict__ tpart) {
    const int b  = blockIdx.y;
    const int mt = blockIdx.x & 3;
    const int ch = blockIdx.x >> 2;
    const int R = nrows[b], C = ncols[b];
    const int lane = threadIdx.x & 63, wv = threadIdx.x >> 6;
    const int m0 = mt * 256;
    const int m  = m0 + lane * 4;
    constexpr int RW = N_DIM / CHUNKS;
    const int n0 = ch * RW;
    const int nend = min(R, n0 + RW);

    __shared__ float rlds[RW > 1024 ? 1 : RW];
    if (!FIRST) {
        for (int i = threadIdx.x; i < RW; i += 256) {
            float uu = u[b * N_DIM + n0 + i];
            rlds[i] = (uu == 0.f) ? 1.f : 1.f / uu;
        }
        __syncthreads();
    }
    float4 acc = make_float4(0.f, 0.f, 0.f, 0.f);
    if (m0 < C) {
        const float* __restrict__ sb = s + (size_t)b * N_DIM * M_DIM;
#pragma unroll 4
        for (int n = n0 + wv; n < nend; n += 4) {
            float4 v = *(const float4*)(sb + (size_t)n * M_DIM + m);
            float rn = FIRST ? 1.f : rlds[n - n0];
            acc.x += rn * (v.x + EPS); acc.y += rn * (v.y + EPS);
            acc.z += rn * (v.z + EPS); acc.w += rn * (v.w + EPS);
        }
    }
    __shared__ float4 red[4][64];
    red[wv][lane] = acc;
    __syncthreads();
    if (wv == 0) {
        float4 a0 = red[0][lane], a1 = red[1][lane],
               a2 = red[2][lane], a3 = red[3][lane];
        float4 t = make_float4(a0.x + a1.x + a2.x + a3.x, a0.y + a1.y + a2.y + a3.y,
                               a0.z + a1.z + a2.z + a3.z, a0.w + a1.w + a2.w + a3.w);
        *(float4*)(tpart + ((size_t)(ch * BATCH + b)) * M_DIM + m) = t;
    }
}

template <int CHUNKS, bool WRITE_C>
__global__ __launch_bounds__(256)
void row_sweep(const float* __restrict__ s, const int* __restrict__ nrows,
               const int* __restrict__ ncols, const float* __restrict__ tpart,
               float* __restrict__ u, float* __restrict__ cOut) {
    const int b = blockIdx.y;
    const int R = nrows[b], C = ncols[b];
    const int n0 = blockIdx.x * 16;
    if (n0 >= R) return;
    __shared__ float clds[M_DIM];
    {
        const int t4 = threadIdx.x;
        float4 sum = make_float4(0.f, 0.f, 0.f, 0.f);
#pragma unroll
        for (int ch = 0; ch < CHUNKS; ++ch) {
            float4 p = *(const float4*)(tpart + ((size_t)(ch * BATCH + b)) * M_DIM + t4 * 4);
            sum.x += p.x; sum.y += p.y; sum.z += p.z; sum.w += p.w;
        }
        float4 cv;
        cv.x = (sum.x == 0.f) ? 1.f : 1.f / sum.x;
        cv.y = (sum.y == 0.f) ? 1.f : 1.f / sum.y;
        cv.z = (sum.z == 0.f) ? 1.f : 1.f / sum.z;
        cv.w = (sum.w == 0.f) ? 1.f : 1.f / sum.w;
        *(float4*)&clds[t4 * 4] = cv;
        if (WRITE_C && blockIdx.x == 0)
            *(float4*)(cOut + b * M_DIM + t4 * 4) = cv;
    }
    __syncthreads();
    const int lane = threadIdx.x & 63, wv = threadIdx.x >> 6;
    const int C4 = C >> 2;
#pragma unroll
    for (int i = 0; i < 4; ++i) {
        const int n = n0 + wv * 4 + i;
        if (n >= R) break;
        const float* __restrict__ srow = s + ((size_t)b * N_DIM + n) * M_DIM;
        float sum = 0.f;
        for (int j = lane; j < C4; j += 64) {
            float4 v  = ((const float4*)srow)[j];
            float4 cc = *(const float4*)&clds[j * 4];
            sum += (v.x + EPS) * cc.x + (v.y + EPS) * cc.y +
                   (v.z + EPS) * cc.z + (v.w + EPS) * cc.w;
        }
        for (int mm = (C4 << 2) + lane; mm < C; mm += 64)
            sum += (srow[mm] + EPS) * clds[mm];
#pragma unroll
        for (int off = 32; off; off >>= 1) sum += __shfl_down(sum, off);
        if (lane == 0) u[b * N_DIM + n] = sum;
    }
}

__global__ __launch_bounds__(256)
void finalize(const float* __restrict__ s, const int* __restrict__ nrows,
              const int* __restrict__ ncols, const float* __restrict__ u,
              const float* __restrict__ c, float* __restrict__ out) {
    const int n = blockIdx.x;
    const int b = blockIdx.y;
    const int R = nrows[b], C = ncols[b];
    const size_t base = ((size_t)b * N_DIM + n) * M_DIM;
    const int m = threadIdx.x * 4;

    float4 o = make_float4(0.f, 0.f, 0.f, 0.f);
    if (n < R && m < C) {
        float uu = u[b * N_DIM + n];
        float rn = (uu == 0.f) ? 1.f : 1.f / uu;
        float4 v  = *(const float4*)(s + base + m);
        float4 cc = *(const float4*)(c + b * M_DIM + m);
        o.x = (m + 0 < C) ? (v.x + EPS) * rn * cc.x : 0.f;
        o.y = (m + 1 < C) ? (v.y + EPS) * rn * cc.y : 0.f;
        o.z = (m + 2 < C) ? (v.z + EPS) * rn * cc.z : 0.f;
        o.w = (m + 3 < C) ? (v.w + EPS) * rn * cc.w : 0.f;
    }
    *(float4*)(out + base + m) = o;
}

// ===========================================================================
extern "C" void kernel_launch(void* const* d_in, const int* in_sizes, int n_in,
                              void* d_out, int out_size, void* d_ws, size_t ws_size,
                              hipStream_t stream) {
    const float* s     = (const float*)d_in[0];
    const int*   nrows = (const int*)d_in[1];
    const int*   ncols = (const int*)d_in[2];
    float*       out   = (float*)d_out;

    const size_t hElems   = (size_t)BATCH * N_DIM * M_DIM;
    const size_t tpElems  = (size_t)CH * BATCH * M_DIM;
    const size_t need_f16 = hElems * 2 + 2 * tpElems * 4;

    if (ws_size >= need_f16) {
        __half* h   = (__half*)d_ws;
        float*  tp0 = (float*)(h + hElems);
        float*  tp1 = tp0 + tpElems;

        dim3 convGrid(4 * CH, BATCH);   // 4096 blocks
        dim3 kGrid(CH, BATCH);          // 1024 blocks

        conv_col0<<<convGrid, 256, 0, stream>>>(s, nrows, ncols, h, tp0);          // i=0
        row_step<false><<<kGrid, 256, 0, stream>>>(h, nrows, ncols, tp0, tp1, out); // i=1 (+i=2 partials)
        row_step<false><<<kGrid, 256, 0, stream>>>(h, nrows, ncols, tp1, tp0, out); // i=3 (+4)
        row_step<false><<<kGrid, 256, 0, stream>>>(h, nrows, ncols, tp0, tp1, out); // i=5 (+6)
        row_step<false><<<kGrid, 256, 0, stream>>>(h, nrows, ncols, tp1, tp0, out); // i=7 (+8)
        row_step<true ><<<kGrid, 256, 0, stream>>>(h, nrows, ncols, tp0, tp1, out); // i=9 + out
        return;
    }

    // f32 fallback
    const size_t need4 = (size_t)(4 * BATCH * M_DIM + BATCH * N_DIM + BATCH * M_DIM) * 4;
    float* tpart = (float*)d_ws;
    if (ws_size >= need4) {
        float* u = tpart + (size_t)4 * BATCH * M_DIM;
        float* c = u + (size_t)BATCH * N_DIM;
        dim3 colGrid(16, BATCH), rowGrid(64, BATCH);
        col_sweep<true, 4><<<colGrid, 256, 0, stream>>>(s, nrows, ncols, u, tpart);
        row_sweep<4, false><<<rowGrid, 256, 0, stream>>>(s, nrows, ncols, tpart, u, c);
        for (int k = 1; k < 4; ++k) {
            col_sweep<false, 4><<<colGrid, 256, 0, stream>>>(s, nrows, ncols, u, tpart);
            row_sweep<4, false><<<rowGrid, 256, 0, stream>>>(s, nrows, ncols, tpart, u, c);
        }
        col_sweep<false, 4><<<colGrid, 256, 0, stream>>>(s, nrows, ncols, u, tpart);
        row_sweep<4, true><<<rowGrid, 256, 0, stream>>>(s, nrows, ncols, tpart, u, c);
        finalize<<<dim3(N_DIM, BATCH), 256, 0, stream>>>(s, nrows, ncols, u, c, out);
    } else {
        float* u = tpart + (size_t)BATCH * M_DIM;
        float* c = u + (size_t)BATCH * N_DIM;
        dim3 colGrid(4, BATCH), rowGrid(64, BATCH);
        col_sweep<true, 1><<<colGrid, 256, 0, stream>>>(s, nrows, ncols, u, tpart);
        row_sweep<1, false><<<rowGrid, 256, 0, stream>>>(s, nrows, ncols, tpart, u, c);
        for (int k = 1; k < 4; ++k) {
            col_sweep<false, 1><<<colGrid, 256, 0, stream>>>(s, nrows, ncols, u, tpart);
            row_sweep<1, false><<<rowGrid, 256, 0, stream>>>(s, nrows, ncols, tpart, u, c);
        }
        col_sweep<false, 1><<<colGrid, 256, 0, stream>>>(s, nrows, ncols, u, tpart);
        row_sweep<1, true><<<rowGrid, 256, 0, stream>>>(s, nrows, ncols, tpart, u, c);
        finalize<<<dim3(N_DIM, BATCH), 256, 0, stream>>>(s, nrows, ncols, u, c, out);
    }
}

// Round 8
// 207.317 us; speedup vs baseline: 1.2906x; 1.0148x over previous
//
#include <hip/hip_runtime.h>
#include <hip/hip_fp16.h>

#define EPS 1e-4f
constexpr int N_DIM  = 1024;
constexpr int M_DIM  = 1024;
constexpr int BATCH  = 64;
constexpr int CH     = 16;            // row chunks per batch
constexpr int CROWS  = N_DIM / CH;    // 64 rows per chunk
constexpr int NPHASE = 5;             // per-batch barriers: after i=0,2,4,6,8

// Factor form: out = r[n]*(s+EPS)*c[m].
// One cooperative kernel, 16 blocks per batch (one per 64-row chunk):
//   conv   : h = fp16(s+EPS) masked; per-thread col partials -> tp0[ch]
//   barrier(b) ; 4x { c = 1/sum_ch tpIn ; per-row r ; tpOut[ch] = sum r*h ; barrier(b) }
//   final  : c from tpIn ; per-row r ; out = r*h*c (zeros for invalid rows/cols)
// Barriers are per-batch (16 blocks) device-scope atomic counters, zeroed by a
// tiny pre-kernel each call (ws is not re-poisoned between graph replays).

__global__ void zero_cnt(unsigned int* cnt) {
    const int t = threadIdx.x;
    if (t < NPHASE * BATCH) cnt[t] = 0u;
}

__device__ __forceinline__ void bat_barrier(unsigned int* cnt, int idx,
                                            unsigned int nact) {
    __syncthreads();
    if (threadIdx.x == 0) {
        __threadfence();                       // release: publish tpart writes
        atomicAdd(&cnt[idx], 1u);
        while (__hip_atomic_load(&cnt[idx], __ATOMIC_ACQUIRE,
                                 __HIP_MEMORY_SCOPE_AGENT) < nact)
            __builtin_amdgcn_s_sleep(8);
    }
    __syncthreads();
    __threadfence();                           // acquire for all threads
}

__global__ __launch_bounds__(256, 4)
void sinkhorn_one(const float* __restrict__ s,
                  const int* __restrict__ nrows,
                  const int* __restrict__ ncols,
                  __half* __restrict__ h,
                  float* __restrict__ tp0,
                  float* __restrict__ tp1,
                  unsigned int* __restrict__ cnt,
                  float* __restrict__ out)
{
    const int b  = blockIdx.y;
    const int ch = blockIdx.x;
    const int R = nrows[b], C = ncols[b];
    const int n0 = ch * CROWS;
    const size_t base = (size_t)b * N_DIM * M_DIM;
    const int tid = threadIdx.x, lane = tid & 63, wv = tid >> 6;

    // Inactive chunk: emit its zero output rows and leave (no barriers).
    if (n0 >= R) {
        const float4 z = make_float4(0.f, 0.f, 0.f, 0.f);
        for (int i = 0; i < CROWS; ++i)
            *(float4*)(out + base + (size_t)(n0 + i) * M_DIM + tid * 4) = z;
        return;
    }

    const unsigned int nact = (unsigned int)((R + CROWS - 1) / CROWS);
    const int nend = min(R, n0 + CROWS);
    const bool hi = (C > 512);

    __shared__ float clds[M_DIM];
    __shared__ float tp_lds[4][M_DIM];

    // ---------------- conv: h = fp16(s+EPS) masked; col partials -> tp0 ----
    {
        const int m = tid * 4;                 // thread owns cols [m, m+4)
        float4 acc = make_float4(0.f, 0.f, 0.f, 0.f);
        if (m < C) {
            for (int n = n0; n < nend; ++n) {
                float4 v = *(const float4*)(s + base + (size_t)n * M_DIM + m);
                v.x += EPS;
                v.y = (m + 1 < C) ? v.y + EPS : 0.f;
                v.z = (m + 2 < C) ? v.z + EPS : 0.f;
                v.w = (m + 3 < C) ? v.w + EPS : 0.f;
                acc.x += v.x; acc.y += v.y; acc.z += v.z; acc.w += v.w;
                union { __half2 h2[2]; uint2 u2; } pk;
                pk.h2[0] = __floats2half2_rn(v.x, v.y);
                pk.h2[1] = __floats2half2_rn(v.z, v.w);
                *(uint2*)(h + base + (size_t)n * M_DIM + m) = pk.u2;
            }
        } else if (m < 512 || hi) {            // hi half skipped when never read
            const uint2 z = make_uint2(0u, 0u);
            for (int n = n0; n < nend; ++n)
                *(uint2*)(h + base + (size_t)n * M_DIM + m) = z;
        }
        *(float4*)(tp0 + (size_t)(ch * BATCH + b) * M_DIM + m) = acc;
    }
    bat_barrier(cnt, 0 * BATCH + b, nact);

    const float* tpIn = tp0;
    float*       tpOut = tp1;

    float crlo[8], crhi[8];

    // ---------------- 4 mid steps: iters (1+2),(3+4),(5+6),(7+8) -----------
    for (int step = 0; step < 4; ++step) {
        {   // c = 1/colsum
            const int m = tid * 4;
            if (m < 512 || hi) {
                float4 sum = make_float4(0.f, 0.f, 0.f, 0.f);
                for (unsigned int cc = 0; cc < nact; ++cc) {
                    float4 p = *(const float4*)(tpIn + (size_t)(cc * BATCH + b) * M_DIM + m);
                    sum.x += p.x; sum.y += p.y; sum.z += p.z; sum.w += p.w;
                }
                float4 cv;
                cv.x = (sum.x == 0.f) ? 1.f : 1.f / sum.x;
                cv.y = (sum.y == 0.f) ? 1.f : 1.f / sum.y;
                cv.z = (sum.z == 0.f) ? 1.f : 1.f / sum.z;
                cv.w = (sum.w == 0.f) ? 1.f : 1.f / sum.w;
                *(float4*)&clds[m] = cv;
            }
        }
        __syncthreads();
        {
            float4 a  = *(const float4*)&clds[lane * 8];
            float4 bb = *(const float4*)&clds[lane * 8 + 4];
            crlo[0]=a.x; crlo[1]=a.y; crlo[2]=a.z; crlo[3]=a.w;
            crlo[4]=bb.x; crlo[5]=bb.y; crlo[6]=bb.z; crlo[7]=bb.w;
            if (hi) {
                float4 d = *(const float4*)&clds[512 + lane * 8];
                float4 e = *(const float4*)&clds[512 + lane * 8 + 4];
                crhi[0]=d.x; crhi[1]=d.y; crhi[2]=d.z; crhi[3]=d.w;
                crhi[4]=e.x; crhi[5]=e.y; crhi[6]=e.z; crhi[7]=e.w;
            }
        }

        float tplo[8] = {0,0,0,0,0,0,0,0};
        float tphi[8] = {0,0,0,0,0,0,0,0};

        for (int i = 0; i < 16; ++i) {
            const int n = n0 + wv * 16 + i;
            if (n >= R) break;                 // rows increase with i
            const __half* hrow = h + base + (size_t)n * M_DIM;
            uint4 rlo = *(const uint4*)(hrow + lane * 8);
            float flo[8], fhi[8];
            {
                const __half2* hp = (const __half2*)&rlo;
#pragma unroll
                for (int k = 0; k < 4; ++k) {
                    float2 f = __half22float2(hp[k]);
                    flo[2*k] = f.x; flo[2*k+1] = f.y;
                }
            }
            float dot = 0.f;
#pragma unroll
            for (int k = 0; k < 8; ++k) dot += flo[k] * crlo[k];
            if (hi) {
                uint4 rhi = *(const uint4*)(hrow + 512 + lane * 8);
                const __half2* hq = (const __half2*)&rhi;
#pragma unroll
                for (int k = 0; k < 4; ++k) {
                    float2 f = __half22float2(hq[k]);
                    fhi[2*k] = f.x; fhi[2*k+1] = f.y;
                }
#pragma unroll
                for (int k = 0; k < 8; ++k) dot += fhi[k] * crhi[k];
            }
#pragma unroll
            for (int off = 32; off; off >>= 1) dot += __shfl_xor(dot, off);
            const float r = (dot == 0.f) ? 1.f : 1.f / dot;
#pragma unroll
            for (int k = 0; k < 8; ++k) tplo[k] += flo[k] * r;
            if (hi) {
#pragma unroll
                for (int k = 0; k < 8; ++k) tphi[k] += fhi[k] * r;
            }
        }

#pragma unroll
        for (int k = 0; k < 8; ++k) tp_lds[wv][lane * 8 + k] = tplo[k];
        if (hi) {
#pragma unroll
            for (int k = 0; k < 8; ++k) tp_lds[wv][512 + lane * 8 + k] = tphi[k];
        }
        __syncthreads();
        {
            const int m = tid * 4;
            if (m < 512 || hi) {
                float4 s0 = *(const float4*)&tp_lds[0][m];
                float4 s1 = *(const float4*)&tp_lds[1][m];
                float4 s2 = *(const float4*)&tp_lds[2][m];
                float4 s3 = *(const float4*)&tp_lds[3][m];
                float4 t = make_float4(s0.x+s1.x+s2.x+s3.x, s0.y+s1.y+s2.y+s3.y,
                                       s0.z+s1.z+s2.z+s3.z, s0.w+s1.w+s2.w+s3.w);
                *(float4*)(tpOut + (size_t)(ch * BATCH + b) * M_DIM + m) = t;
            }
        }
        bat_barrier(cnt, (1 + step) * BATCH + b, nact);
        const float* ti = tpOut; tpOut = (float*)tpIn; tpIn = ti;
    }

    // ---------------- final: iter 9 + output write --------------------------
    {
        const int m = tid * 4;
        if (m < 512 || hi) {
            float4 sum = make_float4(0.f, 0.f, 0.f, 0.f);
            for (unsigned int cc = 0; cc < nact; ++cc) {
                float4 p = *(const float4*)(tpIn + (size_t)(cc * BATCH + b) * M_DIM + m);
                sum.x += p.x; sum.y += p.y; sum.z += p.z; sum.w += p.w;
            }
            float4 cv;
            cv.x = (sum.x == 0.f) ? 1.f : 1.f / sum.x;
            cv.y = (sum.y == 0.f) ? 1.f : 1.f / sum.y;
            cv.z = (sum.z == 0.f) ? 1.f : 1.f / sum.z;
            cv.w = (sum.w == 0.f) ? 1.f : 1.f / sum.w;
            *(float4*)&clds[m] = cv;
        }
    }
    __syncthreads();
    {
        float4 a  = *(const float4*)&clds[lane * 8];
        float4 bb = *(const float4*)&clds[lane * 8 + 4];
        crlo[0]=a.x; crlo[1]=a.y; crlo[2]=a.z; crlo[3]=a.w;
        crlo[4]=bb.x; crlo[5]=bb.y; crlo[6]=bb.z; crlo[7]=bb.w;
        if (hi) {
            float4 d = *(const float4*)&clds[512 + lane * 8];
            float4 e = *(const float4*)&clds[512 + lane * 8 + 4];
            crhi[0]=d.x; crhi[1]=d.y; crhi[2]=d.z; crhi[3]=d.w;
            crhi[4]=e.x; crhi[5]=e.y; crhi[6]=e.z; crhi[7]=e.w;
        }
    }
    const float4 z4 = make_float4(0.f, 0.f, 0.f, 0.f);
    for (int i = 0; i < 16; ++i) {
        const int n = n0 + wv * 16 + i;
        float* orow = out + base + (size_t)n * M_DIM;
        if (n < R) {
            const __half* hrow = h + base + (size_t)n * M_DIM;
            uint4 rlo = *(const uint4*)(hrow + lane * 8);
            float flo[8], fhi[8];
            {
                const __half2* hp = (const __half2*)&rlo;
#pragma unroll
                for (int k = 0; k < 4; ++k) {
                    float2 f = __half22float2(hp[k]);
                    flo[2*k] = f.x; flo[2*k+1] = f.y;
                }
            }
            float dot = 0.f;
#pragma unroll
            for (int k = 0; k < 8; ++k) dot += flo[k] * crlo[k];
            if (hi) {
                uint4 rhi = *(const uint4*)(hrow + 512 + lane * 8);
                const __half2* hq = (const __half2*)&rhi;
#pragma unroll
                for (int k = 0; k < 4; ++k) {
                    float2 f = __half22float2(hq[k]);
                    fhi[2*k] = f.x; fhi[2*k+1] = f.y;
                }
#pragma unroll
                for (int k = 0; k < 8; ++k) dot += fhi[k] * crhi[k];
            }
#pragma unroll
            for (int off = 32; off; off >>= 1) dot += __shfl_xor(dot, off);
            const float r = (dot == 0.f) ? 1.f : 1.f / dot;

            *(float4*)(orow + lane * 8)     = make_float4(flo[0]*r*crlo[0], flo[1]*r*crlo[1],
                                                          flo[2]*r*crlo[2], flo[3]*r*crlo[3]);
            *(float4*)(orow + lane * 8 + 4) = make_float4(flo[4]*r*crlo[4], flo[5]*r*crlo[5],
                                                          flo[6]*r*crlo[6], flo[7]*r*crlo[7]);
            float4 o2 = z4, o3 = z4;
            if (hi) {
                o2 = make_float4(fhi[0]*r*crhi[0], fhi[1]*r*crhi[1],
                                 fhi[2]*r*crhi[2], fhi[3]*r*crhi[3]);
                o3 = make_float4(fhi[4]*r*crhi[4], fhi[5]*r*crhi[5],
                                 fhi[6]*r*crhi[6], fhi[7]*r*crhi[7]);
            }
            *(float4*)(orow + 512 + lane * 8)     = o2;
            *(float4*)(orow + 512 + lane * 8 + 4) = o3;
        } else {
            *(float4*)(orow + lane * 8)           = z4;
            *(float4*)(orow + lane * 8 + 4)       = z4;
            *(float4*)(orow + 512 + lane * 8)     = z4;
            *(float4*)(orow + 512 + lane * 8 + 4) = z4;
        }
    }
}

// ===========================================================================
// Fallback: round-7 six-kernel fp16 pipeline (measured 210 us)
// ===========================================================================
__global__ __launch_bounds__(256)
void conv_col0(const float* __restrict__ s, const int* __restrict__ nrows,
               const int* __restrict__ ncols, __half* __restrict__ h,
               float* __restrict__ tp0) {
    const int b  = blockIdx.y;
    const int mt = blockIdx.x & 3;
    const int ch = blockIdx.x >> 2;
    const int R = nrows[b], C = ncols[b];
    const int n0 = ch * CROWS;
    if (n0 >= R) return;
    const int lane = threadIdx.x & 63, wv = threadIdx.x >> 6;
    const int m = mt * 256 + lane * 4;
    const int nend = min(R, n0 + CROWS);
    const size_t base = (size_t)b * N_DIM * M_DIM;

    float4 acc = make_float4(0.f, 0.f, 0.f, 0.f);
    if (mt * 256 < C) {
        for (int n = n0 + wv; n < nend; n += 4) {
            float4 v = *(const float4*)(s + base + (size_t)n * M_DIM + m);
            v.x = (m + 0 < C) ? v.x + EPS : 0.f;
            v.y = (m + 1 < C) ? v.y + EPS : 0.f;
            v.z = (m + 2 < C) ? v.z + EPS : 0.f;
            v.w = (m + 3 < C) ? v.w + EPS : 0.f;
            acc.x += v.x; acc.y += v.y; acc.z += v.z; acc.w += v.w;
            union { __half2 h2[2]; uint2 u2; } pk;
            pk.h2[0] = __floats2half2_rn(v.x, v.y);
            pk.h2[1] = __floats2half2_rn(v.z, v.w);
            *(uint2*)(h + base + (size_t)n * M_DIM + m) = pk.u2;
        }
    } else {
        const uint2 z = make_uint2(0u, 0u);
        for (int n = n0 + wv; n < nend; n += 4)
            *(uint2*)(h + base + (size_t)n * M_DIM + m) = z;
    }
    __shared__ float4 red[4][64];
    red[wv][lane] = acc;
    __syncthreads();
    if (wv == 0) {
        float4 a0 = red[0][lane], a1 = red[1][lane],
               a2 = red[2][lane], a3 = red[3][lane];
        *(float4*)(tp0 + (size_t)(ch * BATCH + b) * M_DIM + m) =
            make_float4(a0.x+a1.x+a2.x+a3.x, a0.y+a1.y+a2.y+a3.y,
                        a0.z+a1.z+a2.z+a3.z, a0.w+a1.w+a2.w+a3.w);
    }
}

template <bool FINAL>
__global__ __launch_bounds__(256)
void row_step(const __half* __restrict__ h, const int* __restrict__ nrows,
              const int* __restrict__ ncols, const float* __restrict__ tpIn,
              float* __restrict__ tpOut, float* __restrict__ out) {
    const int b  = blockIdx.y;
    const int ch = blockIdx.x;
    const int R = nrows[b], C = ncols[b];
    const int n0 = ch * CROWS;
    if (!FINAL && n0 >= R) return;
    const int lane = threadIdx.x & 63, wv = threadIdx.x >> 6;
    const size_t base = (size_t)b * N_DIM * M_DIM;
    const bool hi = (C > 512);
    const bool anyrows = (n0 < R);

    __shared__ float clds[M_DIM];
    __shared__ float tp_lds[4][M_DIM];

    float crlo[8], crhi[8];
    if (anyrows) {
        const int nch = min(CH, (R + CROWS - 1) / CROWS);
        const int t4 = threadIdx.x * 4;
        if (hi || t4 < 512) {
            float4 sum = make_float4(0.f, 0.f, 0.f, 0.f);
            for (int cc = 0; cc < nch; ++cc) {
                float4 p = *(const float4*)(tpIn + (size_t)(cc * BATCH + b) * M_DIM + t4);
                sum.x += p.x; sum.y += p.y; sum.z += p.z; sum.w += p.w;
            }
            float4 cv;
            cv.x = (sum.x == 0.f) ? 1.f : 1.f / sum.x;
            cv.y = (sum.y == 0.f) ? 1.f : 1.f / sum.y;
            cv.z = (sum.z == 0.f) ? 1.f : 1.f / sum.z;
            cv.w = (sum.w == 0.f) ? 1.f : 1.f / sum.w;
            *(float4*)&clds[t4] = cv;
        }
        __syncthreads();
        float4 a = *(const float4*)&clds[lane * 8];
        float4 bb = *(const float4*)&clds[lane * 8 + 4];
        crlo[0]=a.x; crlo[1]=a.y; crlo[2]=a.z; crlo[3]=a.w;
        crlo[4]=bb.x; crlo[5]=bb.y; crlo[6]=bb.z; crlo[7]=bb.w;
        if (hi) {
            float4 d = *(const float4*)&clds[512 + lane * 8];
            float4 e = *(const float4*)&clds[512 + lane * 8 + 4];
            crhi[0]=d.x; crhi[1]=d.y; crhi[2]=d.z; crhi[3]=d.w;
            crhi[4]=e.x; crhi[5]=e.y; crhi[6]=e.z; crhi[7]=e.w;
        }
    }

    float tplo[8] = {0,0,0,0,0,0,0,0};
    float tphi[8] = {0,0,0,0,0,0,0,0};

    for (int i = 0; i < 16; ++i) {
        const int n = n0 + wv * 16 + i;
        if (n < R) {
            const __half* hrow = h + base + (size_t)n * M_DIM;
            uint4 rlo = *(const uint4*)(hrow + lane * 8);
            float flo[8], fhi[8];
            const __half2* hp = (const __half2*)&rlo;
#pragma unroll
            for (int k = 0; k < 4; ++k) {
                float2 f = __half22float2(hp[k]);
                flo[2*k] = f.x; flo[2*k+1] = f.y;
            }
            float dot = 0.f;
#pragma unroll
            for (int k = 0; k < 8; ++k) dot += flo[k] * crlo[k];
            if (hi) {
                uint4 rhi = *(const uint4*)(hrow + 512 + lane * 8);
                const __half2* hq = (const __half2*)&rhi;
#pragma unroll
                for (int k = 0; k < 4; ++k) {
                    float2 f = __half22float2(hq[k]);
                    fhi[2*k] = f.x; fhi[2*k+1] = f.y;
                }
#pragma unroll
                for (int k = 0; k < 8; ++k) dot += fhi[k] * crhi[k];
            }
#pragma unroll
            for (int off = 32; off; off >>= 1) dot += __shfl_xor(dot, off);
            const float r = (dot == 0.f) ? 1.f : 1.f / dot;

            if (FINAL) {
                float* orow = out + base + (size_t)n * M_DIM;
                *(float4*)(orow + lane * 8)     = make_float4(flo[0]*r*crlo[0], flo[1]*r*crlo[1],
                                                              flo[2]*r*crlo[2], flo[3]*r*crlo[3]);
                *(float4*)(orow + lane * 8 + 4) = make_float4(flo[4]*r*crlo[4], flo[5]*r*crlo[5],
                                                              flo[6]*r*crlo[6], flo[7]*r*crlo[7]);
                float4 o2 = make_float4(0.f,0.f,0.f,0.f), o3 = o2;
                if (hi) {
                    o2 = make_float4(fhi[0]*r*crhi[0], fhi[1]*r*crhi[1],
                                     fhi[2]*r*crhi[2], fhi[3]*r*crhi[3]);
                    o3 = make_float4(fhi[4]*r*crhi[4], fhi[5]*r*crhi[5],
                                     fhi[6]*r*crhi[6], fhi[7]*r*crhi[7]);
                }
                *(float4*)(orow + 512 + lane * 8)     = o2;
                *(float4*)(orow + 512 + lane * 8 + 4) = o3;
            } else {
#pragma unroll
                for (int k = 0; k < 8; ++k) tplo[k] += flo[k] * r;
                if (hi) {
#pragma unroll
                    for (int k = 0; k < 8; ++k) tphi[k] += fhi[k] * r;
                }
            }
        } else if (FINAL) {
            float* orow = out + base + (size_t)n * M_DIM;
            const float4 z = make_float4(0.f, 0.f, 0.f, 0.f);
            *(float4*)(orow + lane * 8)           = z;
            *(float4*)(orow + lane * 8 + 4)       = z;
            *(float4*)(orow + 512 + lane * 8)     = z;
            *(float4*)(orow + 512 + lane * 8 + 4) = z;
        }
    }

    if (!FINAL) {
#pragma unroll
        for (int k = 0; k < 8; ++k) tp_lds[wv][lane * 8 + k] = tplo[k];
        if (hi) {
#pragma unroll
            for (int k = 0; k < 8; ++k) tp_lds[wv][512 + lane * 8 + k] = tphi[k];
        }
        __syncthreads();
        const int t4 = threadIdx.x * 4;
        if (hi || t4 < 512) {
            float4 s0 = *(const float4*)&tp_lds[0][t4];
            float4 s1 = *(const float4*)&tp_lds[1][t4];
            float4 s2 = *(const float4*)&tp_lds[2][t4];
            float4 s3 = *(const float4*)&tp_lds[3][t4];
            *(float4*)(tpOut + (size_t)(ch * BATCH + b) * M_DIM + t4) =
                make_float4(s0.x+s1.x+s2.x+s3.x, s0.y+s1.y+s2.y+s3.y,
                            s0.z+s1.z+s2.z+s3.z, s0.w+s1.w+s2.w+s3.w);
        }
    }
}

// ===========================================================================
extern "C" void kernel_launch(void* const* d_in, const int* in_sizes, int n_in,
                              void* d_out, int out_size, void* d_ws, size_t ws_size,
                              hipStream_t stream) {
    const float* s     = (const float*)d_in[0];
    const int*   nrows = (const int*)d_in[1];
    const int*   ncols = (const int*)d_in[2];
    float*       out   = (float*)d_out;

    const size_t hElems  = (size_t)BATCH * N_DIM * M_DIM;
    const size_t tpElems = (size_t)CH * BATCH * M_DIM;
    const size_t need    = hElems * 2 + 2 * tpElems * 4 + NPHASE * BATCH * 4;

    if (ws_size >= need) {
        __half* h   = (__half*)d_ws;
        float*  tp0 = (float*)(h + hElems);
        float*  tp1 = tp0 + tpElems;
        unsigned int* cnt = (unsigned int*)(tp1 + tpElems);

        int dev = 0, numCU = 0, perCU = 0;
        hipGetDevice(&dev);
        hipDeviceGetAttribute(&numCU, hipDeviceAttributeMultiprocessorCount, dev);
        hipOccupancyMaxActiveBlocksPerMultiprocessor(&perCU, sinkhorn_one, 256, 0);

        if ((long long)perCU * numCU >= CH * BATCH) {
            zero_cnt<<<1, 320, 0, stream>>>(cnt);
            void* args[] = {(void*)&s, (void*)&nrows, (void*)&ncols, (void*)&h,
                            (void*)&tp0, (void*)&tp1, (void*)&cnt, (void*)&out};
            hipLaunchCooperativeKernel((void*)sinkhorn_one, dim3(CH, BATCH),
                                       dim3(256), args, 0, stream);
            return;
        }

        // round-7 six-kernel fallback
        dim3 convGrid(4 * CH, BATCH), kGrid(CH, BATCH);
        conv_col0<<<convGrid, 256, 0, stream>>>(s, nrows, ncols, h, tp0);
        row_step<false><<<kGrid, 256, 0, stream>>>(h, nrows, ncols, tp0, tp1, out);
        row_step<false><<<kGrid, 256, 0, stream>>>(h, nrows, ncols, tp1, tp0, out);
        row_step<false><<<kGrid, 256, 0, stream>>>(h, nrows, ncols, tp0, tp1, out);
        row_step<false><<<kGrid, 256, 0, stream>>>(h, nrows, ncols, tp1, tp0, out);
        row_step<true ><<<kGrid, 256, 0, stream>>>(h, nrows, ncols, tp0, tp1, out);
        return;
    }
    // (ws is ~1 GB in this harness; no tiny-ws path needed beyond this point.)
}